// Round 3
// baseline (381.546 us; speedup 1.0000x reference)
//
#include <hip/hip_runtime.h>
#include <hip/hip_bf16.h>
#include <stdint.h>

#define D_MODEL 1024
#define NH 16
#define DH 64
#define SEQ 2048
#define MROWS 4096   // B*S

typedef unsigned short ushort_t;
typedef __attribute__((ext_vector_type(4))) float f32x4;
typedef __attribute__((ext_vector_type(4))) unsigned short us4;
typedef __attribute__((ext_vector_type(8))) unsigned short us8;
typedef __attribute__((ext_vector_type(8))) __bf16 bf16x8;

__device__ __forceinline__ f32x4 mfma16(us8 a, us8 b, f32x4 c) {
    return __builtin_amdgcn_mfma_f32_16x16x32_bf16(
        __builtin_bit_cast(bf16x8, a), __builtin_bit_cast(bf16x8, b), c, 0, 0, 0);
}

// fp32 -> bf16 round-to-nearest-even (finite inputs)
__device__ __forceinline__ ushort_t f2bf(float f) {
    union { float f; uint32_t u; } v; v.f = f;
    uint32_t r = v.u + 0x7fffu + ((v.u >> 16) & 1u);
    return (ushort_t)(r >> 16);
}

// async global->LDS, 16B per lane; LDS base wave-uniform, lane i at base+i*16
__device__ __forceinline__ void gload16(const void* g, void* l) {
    __builtin_amdgcn_global_load_lds(
        (const __attribute__((address_space(1))) void*)g,
        (__attribute__((address_space(3))) void*)l, 16, 0, 0);
}

// ---------------------------------------------------------------------------
// fused fp32 -> bf16 convert; blockIdx.z picks (src,dst) pair; n4 = float4 count
// ---------------------------------------------------------------------------
__global__ __launch_bounds__(256) void conv_multi(
    const float* __restrict__ s0, ushort_t* __restrict__ d0,
    const float* __restrict__ s1, ushort_t* __restrict__ d1,
    const float* __restrict__ s2, ushort_t* __restrict__ d2,
    const float* __restrict__ s3, ushort_t* __restrict__ d3, int n4)
{
    int z = blockIdx.z;
    const float* s = z == 0 ? s0 : z == 1 ? s1 : z == 2 ? s2 : s3;
    ushort_t* d    = z == 0 ? d0 : z == 1 ? d1 : z == 2 ? d2 : d3;
    int i = blockIdx.x * 256 + threadIdx.x;
    int stride = gridDim.x * 256;
    for (; i < n4; i += stride) {
        float4 v = ((const float4*)s)[i];
        us4 o;
        o[0] = f2bf(v.x); o[1] = f2bf(v.y); o[2] = f2bf(v.z); o[3] = f2bf(v.w);
        ((us4*)d)[i] = o;
    }
}

// ---------------------------------------------------------------------------
// mask tile flags at 64x64 granularity
// ---------------------------------------------------------------------------
__global__ __launch_bounds__(256) void mask_flags(const float* __restrict__ mask,
                                                  int* __restrict__ flags)
{
    int qt = blockIdx.x, kt = blockIdx.y;
    int t = threadIdx.x;
    bool nz = false;
#pragma unroll
    for (int i = 0; i < 4; i++) {
        int idx = t + i * 256;               // 1024 float4: 64 rows x 16
        int row = idx >> 4, c4 = (idx & 15) * 4;
        float4 v = *(const float4*)(mask + (size_t)(qt * 64 + row) * SEQ + kt * 64 + c4);
        nz |= (v.x != 0.f) | (v.y != 0.f) | (v.z != 0.f) | (v.w != 0.f);
    }
    if (__any((int)nz) && (t & 63) == 0) atomicOr(&flags[qt * 32 + kt], 1);
}

// ---------------------------------------------------------------------------
// shared GEMM core: C(acc) = A[4096][1024] @ W^T, BM=128 BN=64 BK=64,
// global_load_lds 16B staging (m97 structure)
// ---------------------------------------------------------------------------
__device__ __forceinline__ void gemm_core(const ushort_t* __restrict__ A,
                                          const ushort_t* __restrict__ B,
                                          int m0, int n0, int t,
                                          ushort_t* sA, ushort_t* sB,
                                          f32x4 acc[4][2])
{
    const int lane = t & 63, w = t >> 6;
    const int lr = lane & 15, lg = lane >> 4;
    const int wm = (w >> 1) * 64, wn = (w & 1) * 32;

    for (int k0 = 0; k0 < D_MODEL; k0 += 64) {
        __syncthreads();
#pragma unroll
        for (int r = 0; r < 4; r++) {
            int chunk = r * 256 + t;                   // 1024 chunks of 8 bf16
            int row = chunk >> 3, c8 = (chunk & 7) * 8;
            gload16(A + (size_t)(m0 + row) * D_MODEL + k0 + c8,
                    &sA[(r * 256 + w * 64) * 8]);
        }
#pragma unroll
        for (int r = 0; r < 2; r++) {
            int chunk = r * 256 + t;
            int row = chunk >> 3, c8 = (chunk & 7) * 8;
            gload16(B + (size_t)(n0 + row) * D_MODEL + k0 + c8,
                    &sB[(r * 256 + w * 64) * 8]);
        }
        __syncthreads();

        us8 af[4][2], bfr[2][2];
#pragma unroll
        for (int i = 0; i < 4; i++)
#pragma unroll
            for (int ks = 0; ks < 2; ks++)
                af[i][ks] = *(const us8*)&sA[(wm + i * 16 + lr) * 64 + ks * 32 + 8 * lg];
#pragma unroll
        for (int j = 0; j < 2; j++)
#pragma unroll
            for (int ks = 0; ks < 2; ks++)
                bfr[j][ks] = *(const us8*)&sB[(wn + j * 16 + lr) * 64 + ks * 32 + 8 * lg];
#pragma unroll
        for (int i = 0; i < 4; i++)
#pragma unroll
            for (int j = 0; j < 2; j++)
#pragma unroll
                for (int ks = 0; ks < 2; ks++)
                    acc[i][j] = mfma16(af[i][ks], bfr[j][ks], acc[i][j]);
    }
}

// Q/K projections (z=0: Q scaled by 0.125, z=1: K). C layout [B,H,S,Dh] bf16.
__global__ __launch_bounds__(256) void gemm_qk(const ushort_t* __restrict__ A0,
                                               const ushort_t* __restrict__ A1,
                                               const ushort_t* __restrict__ Wq,
                                               const ushort_t* __restrict__ Wk,
                                               ushort_t* __restrict__ Qo,
                                               ushort_t* __restrict__ Ko)
{
    __shared__ ushort_t sA[128 * 64];
    __shared__ ushort_t sB[64 * 64];
    const int z = blockIdx.z;
    const ushort_t* A = z ? A1 : A0;
    const ushort_t* W = z ? Wk : Wq;
    ushort_t* C = z ? Ko : Qo;
    const float scale = z ? 1.0f : 0.125f;
    const int t = threadIdx.x, lane = t & 63, w = t >> 6;
    const int lr = lane & 15, lg = lane >> 4;
    const int wm = (w >> 1) * 64, wn = (w & 1) * 32;
    const int m0 = blockIdx.x * 128, n0 = blockIdx.y * 64;

    f32x4 acc[4][2];
    f32x4 zero = {0.f, 0.f, 0.f, 0.f};
#pragma unroll
    for (int i = 0; i < 4; i++)
#pragma unroll
        for (int j = 0; j < 2; j++) acc[i][j] = zero;
    gemm_core(A, W, m0, n0, t, sA, sB, acc);

#pragma unroll
    for (int i = 0; i < 4; i++)
#pragma unroll
        for (int j = 0; j < 2; j++)
#pragma unroll
            for (int r = 0; r < 4; r++) {
                int m = m0 + wm + i * 16 + 4 * lg + r;   // token (b*S+s)
                int n = n0 + wn + j * 16 + lr;           // feature
                int b = m >> 11, s = m & 2047;
                int h = n >> 6, dh = n & 63;
                C[(((size_t)(b * NH + h)) * SEQ + s) * DH + dh] = f2bf(acc[i][j][r] * scale);
            }
}

// V projection -> transposed output VT [B,H,Dh,S] bf16 (r-packed us4 stores)
__global__ __launch_bounds__(256) void gemm_v(const ushort_t* __restrict__ A,
                                              const ushort_t* __restrict__ W,
                                              ushort_t* __restrict__ VT)
{
    __shared__ ushort_t sA[128 * 64];
    __shared__ ushort_t sB[64 * 64];
    const int t = threadIdx.x, lane = t & 63, w = t >> 6;
    const int lr = lane & 15, lg = lane >> 4;
    const int wm = (w >> 1) * 64, wn = (w & 1) * 32;
    const int m0 = blockIdx.x * 128, n0 = blockIdx.y * 64;

    f32x4 acc[4][2];
    f32x4 zero = {0.f, 0.f, 0.f, 0.f};
#pragma unroll
    for (int i = 0; i < 4; i++)
#pragma unroll
        for (int j = 0; j < 2; j++) acc[i][j] = zero;
    gemm_core(A, W, m0, n0, t, sA, sB, acc);

#pragma unroll
    for (int i = 0; i < 4; i++)
#pragma unroll
        for (int j = 0; j < 2; j++) {
            int m = m0 + wm + i * 16 + 4 * lg;           // s base; r adds 0..3
            int n = n0 + wn + j * 16 + lr;
            int b = m >> 11, s = m & 2047;
            int h = n >> 6, dh = n & 63;
            us4 o;
#pragma unroll
            for (int r = 0; r < 4; r++) o[r] = f2bf(acc[i][j][r]);
            *(us4*)&VT[(((size_t)(b * NH + h)) * DH + dh) * SEQ + s] = o;
        }
}

// output projection: A bf16 [4096][1024] @ W0^T -> fp32 [4096][1024]
__global__ __launch_bounds__(256) void gemm_o(const ushort_t* __restrict__ A,
                                              const ushort_t* __restrict__ W,
                                              float* __restrict__ C)
{
    __shared__ ushort_t sA[128 * 64];
    __shared__ ushort_t sB[64 * 64];
    const int t = threadIdx.x, lane = t & 63, w = t >> 6;
    const int lr = lane & 15, lg = lane >> 4;
    const int wm = (w >> 1) * 64, wn = (w & 1) * 32;
    const int m0 = blockIdx.x * 128, n0 = blockIdx.y * 64;

    f32x4 acc[4][2];
    f32x4 zero = {0.f, 0.f, 0.f, 0.f};
#pragma unroll
    for (int i = 0; i < 4; i++)
#pragma unroll
        for (int j = 0; j < 2; j++) acc[i][j] = zero;
    gemm_core(A, W, m0, n0, t, sA, sB, acc);

#pragma unroll
    for (int i = 0; i < 4; i++)
#pragma unroll
        for (int j = 0; j < 2; j++)
#pragma unroll
            for (int r = 0; r < 4; r++) {
                int m = m0 + wm + i * 16 + 4 * lg + r;
                int n = n0 + wn + j * 16 + lr;
                C[(size_t)m * D_MODEL + n] = acc[i][j][r];
            }
}

// ---------------------------------------------------------------------------
// Flash attention, barrier-free: K and V^T fragments straight from global
// (L2-resident: 512 KB per head). Only per-wave sP in LDS. 4 waves x 16 q-rows.
// Q pre-scaled. l computed via MFMA with ones-fragment. Defer-max (THR=8).
// ---------------------------------------------------------------------------
__global__ __launch_bounds__(256) void attn_fwd(const ushort_t* __restrict__ Q,
                                                const ushort_t* __restrict__ K,
                                                const ushort_t* __restrict__ VT,
                                                const float* __restrict__ mask,
                                                const int* __restrict__ flags,
                                                ushort_t* __restrict__ O)
{
    __shared__ ushort_t sP[4][16 * 64];     // per-wave P tile [16 q][64 kv]

    const int t = threadIdx.x, lane = t & 63, w = t >> 6;
    const int lr = lane & 15, lg = lane >> 4;
    const int qt = blockIdx.x, bh = blockIdx.y;
    const int b = bh >> 4, h = bh & 15;
    const int q0 = qt * 64 + w * 16;

    // hoist mask-tile flags into one wave bitmask
    unsigned long long fl = __ballot(lane < 32 ? (flags[qt * 32 + lane] != 0) : 0);

    // Q fragments (row = q0+lr, k-contiguous)
    us8 qf[2];
#pragma unroll
    for (int ks = 0; ks < 2; ks++)
        qf[ks] = *(const us8*)(Q + ((size_t)bh * SEQ + q0 + lr) * DH + ks * 32 + 8 * lg);

    f32x4 zero = {0.f, 0.f, 0.f, 0.f};
    f32x4 acc_o[4];
#pragma unroll
    for (int fd = 0; fd < 4; fd++) acc_o[fd] = zero;
    f32x4 acc_l = zero;
    float m_run[4];
#pragma unroll
    for (int r = 0; r < 4; r++) m_run[r] = -1e30f;

    // lane-dependent base pointers
    const ushort_t* Kb = K  + (size_t)bh * SEQ * DH + lr * DH + 8 * lg;
    const ushort_t* Vb = VT + (size_t)bh * DH * SEQ + lr * SEQ + 8 * lg;
    char* cP = (char*)(&sP[w][0]);

    us8 ones;
#pragma unroll
    for (int i = 0; i < 8; i++) ones[i] = 0x3F80;   // bf16 1.0

    for (int kvt = 0; kvt < SEQ / 64; ++kvt) {
        // ---- K fragments from global (L2) ----
        us8 kf[4][2];
#pragma unroll
        for (int fn = 0; fn < 4; fn++)
#pragma unroll
            for (int ks = 0; ks < 2; ks++)
                kf[fn][ks] = *(const us8*)(Kb + (size_t)(kvt * 64 + fn * 16) * DH + ks * 32);

        // ---- scores = Q K^T (Q pre-scaled) ----
        f32x4 sacc[4];
#pragma unroll
        for (int fn = 0; fn < 4; fn++) sacc[fn] = zero;
#pragma unroll
        for (int fn = 0; fn < 4; fn++)
#pragma unroll
            for (int ks = 0; ks < 2; ks++)
                sacc[fn] = mfma16(qf[ks], kf[fn][ks], sacc[fn]);

        // ---- prefetch V^T fragments now; latency hides under softmax ----
        us8 vf[4][2];
#pragma unroll
        for (int fd = 0; fd < 4; fd++)
#pragma unroll
            for (int ks = 0; ks < 2; ks++)
                vf[fd][ks] = *(const us8*)(Vb + (size_t)fd * 16 * SEQ + kvt * 64 + ks * 32);

        // ---- additive mask (skipped when tile all-zero) ----
        if ((fl >> kvt) & 1ULL) {
#pragma unroll
            for (int r = 0; r < 4; r++) {
                int q = q0 + 4 * lg + r;
#pragma unroll
                for (int fn = 0; fn < 4; fn++)
                    sacc[fn][r] += mask[(size_t)q * SEQ + kvt * 64 + fn * 16 + lr];
            }
        }

        // ---- row max (16-lane reduce) + defer-max rescale ----
        float mx[4];
#pragma unroll
        for (int r = 0; r < 4; r++) {
            float m = fmaxf(fmaxf(sacc[0][r], sacc[1][r]), fmaxf(sacc[2][r], sacc[3][r]));
#pragma unroll
            for (int off = 1; off < 16; off <<= 1) m = fmaxf(m, __shfl_xor(m, off));
            mx[r] = m;
        }
        bool need = (mx[0] > m_run[0] + 8.f) | (mx[1] > m_run[1] + 8.f) |
                    (mx[2] > m_run[2] + 8.f) | (mx[3] > m_run[3] + 8.f);
        if (__any((int)need)) {
#pragma unroll
            for (int r = 0; r < 4; r++) {
                float mn = fmaxf(m_run[r], mx[r]);
                float sc = __expf(m_run[r] - mn);
                m_run[r] = mn;
                acc_l[r] *= sc;
#pragma unroll
                for (int fd = 0; fd < 4; fd++) acc_o[fd][r] *= sc;
            }
        }

        // ---- P = exp(S - m), pack bf16 to per-wave LDS (swizzled) ----
#pragma unroll
        for (int r = 0; r < 4; r++) {
            int qr = 4 * lg + r;
#pragma unroll
            for (int fn = 0; fn < 4; fn++) {
                float p = __expf(sacc[fn][r] - m_run[r]);
                int by = (qr * 128 + (fn * 16 + lr) * 2) ^ ((qr & 7) << 4);
                *(ushort_t*)(cP + by) = f2bf(p);
            }
        }

        // ---- O += P @ V ; l += P @ 1 ----
#pragma unroll
        for (int ks = 0; ks < 2; ks++) {
            int byp = (lr * 128 + (ks * 32 + 8 * lg) * 2) ^ ((lr & 7) << 4);
            us8 pf = *(const us8*)(cP + byp);
            acc_l = mfma16(pf, ones, acc_l);
#pragma unroll
            for (int fd = 0; fd < 4; fd++)
                acc_o[fd] = mfma16(pf, vf[fd][ks], acc_o[fd]);
        }
    }

    // ---- normalize + write [B*S][D] bf16 ----
#pragma unroll
    for (int r = 0; r < 4; r++) {
        float inv = 1.f / acc_l[r];
        int q = q0 + 4 * lg + r;
#pragma unroll
        for (int fd = 0; fd < 4; fd++)
            O[((size_t)(b * SEQ + q)) * D_MODEL + h * DH + fd * 16 + lr] =
                f2bf(acc_o[fd][r] * inv);
    }
}

// ---------------------------------------------------------------------------
extern "C" void kernel_launch(void* const* d_in, const int* in_sizes, int n_in,
                              void* d_out, int out_size, void* d_ws, size_t ws_size,
                              hipStream_t stream)
{
    const float* qx   = (const float*)d_in[0];
    const float* kx   = (const float*)d_in[1];
    const float* vx   = (const float*)d_in[2];
    const float* mask = (const float*)d_in[3];
    const float* wq   = (const float*)d_in[4];
    const float* wk   = (const float*)d_in[5];
    const float* wv   = (const float*)d_in[6];
    const float* w0   = (const float*)d_in[7];
    float* out = (float*)d_out;

    char* ws = (char*)d_ws;
    const size_t MB = 1024 * 1024;
    ushort_t* A0 = (ushort_t*)(ws);                 // 8 MB (qx bf16, then vx bf16)
    ushort_t* A1 = (ushort_t*)(ws + 8 * MB);        // 8 MB (kx bf16, then AO)
    ushort_t* Wq = (ushort_t*)(ws + 16 * MB);       // 2 MB each
    ushort_t* Wk = (ushort_t*)(ws + 18 * MB);
    ushort_t* Wv = (ushort_t*)(ws + 20 * MB);
    ushort_t* W0 = (ushort_t*)(ws + 22 * MB);
    ushort_t* VT = (ushort_t*)(ws + 24 * MB);       // [B,H,Dh,S] bf16, 8 MB
    int* flags   = (int*)(ws + 32 * MB);            // [32][32]
    ushort_t* AO = A1;                              // attn out reuses A1
    // Q and K (bf16, [B,H,S,Dh]) live in d_out until attn consumes them
    ushort_t* Qb = (ushort_t*)d_out;
    ushort_t* Kb = (ushort_t*)d_out + 4 * MB;       // +8 MB bytes

    hipMemsetAsync(flags, 0, 32 * 32 * sizeof(int), stream);
    mask_flags<<<dim3(32, 32), 256, 0, stream>>>(mask, flags);

    // weights fp32 -> bf16 (one fused launch)
    conv_multi<<<dim3(256, 1, 4), 256, 0, stream>>>(wq, Wq, wk, Wk, wv, Wv, w0, W0, 262144);
    // qx, kx fp32 -> bf16
    conv_multi<<<dim3(1024, 1, 2), 256, 0, stream>>>(qx, A0, kx, A1, qx, A0, qx, A0, 1048576);

    gemm_qk<<<dim3(32, 16, 2), 256, 0, stream>>>(A0, A1, Wq, Wk, Qb, Kb);

    // vx fp32 -> bf16 (A0 free after gemm_qk)
    conv_multi<<<dim3(1024, 1, 1), 256, 0, stream>>>(vx, A0, vx, A0, vx, A0, vx, A0, 1048576);
    gemm_v<<<dim3(32, 16), 256, 0, stream>>>(A0, Wv, VT);

    attn_fwd<<<dim3(32, 32), 256, 0, stream>>>(Qb, Kb, VT, mask, flags, AO);

    gemm_o<<<dim3(32, 16), 256, 0, stream>>>(AO, W0, out);
}

// Round 4
// 189.675 us; speedup vs baseline: 2.0116x; 2.0116x over previous
//
#include <hip/hip_runtime.h>
#include <hip/hip_bf16.h>
#include <stdint.h>

#define D_MODEL 1024
#define NH 16
#define DH 64
#define SEQ 2048
#define MROWS 4096   // B*S

typedef unsigned short ushort_t;
typedef __attribute__((ext_vector_type(4))) float f32x4;
typedef __attribute__((ext_vector_type(4))) unsigned short us4;
typedef __attribute__((ext_vector_type(8))) unsigned short us8;
typedef __attribute__((ext_vector_type(8))) __bf16 bf16x8;

__device__ __forceinline__ f32x4 mfma16(us8 a, us8 b, f32x4 c) {
    return __builtin_amdgcn_mfma_f32_16x16x32_bf16(
        __builtin_bit_cast(bf16x8, a), __builtin_bit_cast(bf16x8, b), c, 0, 0, 0);
}

// fp32 -> bf16 round-to-nearest-even (finite inputs)
__device__ __forceinline__ ushort_t f2bf(float f) {
    union { float f; uint32_t u; } v; v.f = f;
    uint32_t r = v.u + 0x7fffu + ((v.u >> 16) & 1u);
    return (ushort_t)(r >> 16);
}

// async global->LDS, 16B per lane; LDS base wave-uniform, lane i at base+i*16
__device__ __forceinline__ void gload16(const void* g, void* l) {
    __builtin_amdgcn_global_load_lds(
        (const __attribute__((address_space(1))) void*)g,
        (__attribute__((address_space(3))) void*)l, 16, 0, 0);
}

// ---------------------------------------------------------------------------
// fused fp32 -> bf16 convert; blockIdx.z picks (src,dst) pair; n4 = float4 count
// ---------------------------------------------------------------------------
__global__ __launch_bounds__(256) void conv_multi(
    const float* __restrict__ s0, ushort_t* __restrict__ d0,
    const float* __restrict__ s1, ushort_t* __restrict__ d1,
    const float* __restrict__ s2, ushort_t* __restrict__ d2,
    const float* __restrict__ s3, ushort_t* __restrict__ d3, int n4)
{
    int z = blockIdx.z;
    const float* s = z == 0 ? s0 : z == 1 ? s1 : z == 2 ? s2 : s3;
    ushort_t* d    = z == 0 ? d0 : z == 1 ? d1 : z == 2 ? d2 : d3;
    int i = blockIdx.x * 256 + threadIdx.x;
    int stride = gridDim.x * 256;
    for (; i < n4; i += stride) {
        float4 v = ((const float4*)s)[i];
        us4 o;
        o[0] = f2bf(v.x); o[1] = f2bf(v.y); o[2] = f2bf(v.z); o[3] = f2bf(v.w);
        ((us4*)d)[i] = o;
    }
}

// ---------------------------------------------------------------------------
// mask tile flags at 64x64 granularity
// ---------------------------------------------------------------------------
__global__ __launch_bounds__(256) void mask_flags(const float* __restrict__ mask,
                                                  int* __restrict__ flags)
{
    int qt = blockIdx.x, kt = blockIdx.y;
    int t = threadIdx.x;
    bool nz = false;
#pragma unroll
    for (int i = 0; i < 4; i++) {
        int idx = t + i * 256;               // 1024 float4: 64 rows x 16
        int row = idx >> 4, c4 = (idx & 15) * 4;
        float4 v = *(const float4*)(mask + (size_t)(qt * 64 + row) * SEQ + kt * 64 + c4);
        nz |= (v.x != 0.f) | (v.y != 0.f) | (v.z != 0.f) | (v.w != 0.f);
    }
    if (__any((int)nz) && (t & 63) == 0) atomicOr(&flags[qt * 32 + kt], 1);
}

// ---------------------------------------------------------------------------
// shared GEMM core: C(acc) = A[4096][1024] @ W^T, BM=128 BN=64 BK=64,
// global_load_lds 16B staging (m97 structure)
// ---------------------------------------------------------------------------
__device__ __forceinline__ void gemm_core(const ushort_t* __restrict__ A,
                                          const ushort_t* __restrict__ B,
                                          int m0, int n0, int t,
                                          ushort_t* sA, ushort_t* sB,
                                          f32x4 acc[4][2])
{
    const int lane = t & 63, w = t >> 6;
    const int lr = lane & 15, lg = lane >> 4;
    const int wm = (w >> 1) * 64, wn = (w & 1) * 32;

    for (int k0 = 0; k0 < D_MODEL; k0 += 64) {
        __syncthreads();
#pragma unroll
        for (int r = 0; r < 4; r++) {
            int chunk = r * 256 + t;                   // 1024 chunks of 8 bf16
            int row = chunk >> 3, c8 = (chunk & 7) * 8;
            gload16(A + (size_t)(m0 + row) * D_MODEL + k0 + c8,
                    &sA[(r * 256 + w * 64) * 8]);
        }
#pragma unroll
        for (int r = 0; r < 2; r++) {
            int chunk = r * 256 + t;
            int row = chunk >> 3, c8 = (chunk & 7) * 8;
            gload16(B + (size_t)(n0 + row) * D_MODEL + k0 + c8,
                    &sB[(r * 256 + w * 64) * 8]);
        }
        __syncthreads();

        us8 af[4][2], bfr[2][2];
#pragma unroll
        for (int i = 0; i < 4; i++)
#pragma unroll
            for (int ks = 0; ks < 2; ks++)
                af[i][ks] = *(const us8*)&sA[(wm + i * 16 + lr) * 64 + ks * 32 + 8 * lg];
#pragma unroll
        for (int j = 0; j < 2; j++)
#pragma unroll
            for (int ks = 0; ks < 2; ks++)
                bfr[j][ks] = *(const us8*)&sB[(wn + j * 16 + lr) * 64 + ks * 32 + 8 * lg];
#pragma unroll
        for (int i = 0; i < 4; i++)
#pragma unroll
            for (int j = 0; j < 2; j++)
#pragma unroll
                for (int ks = 0; ks < 2; ks++)
                    acc[i][j] = mfma16(af[i][ks], bfr[j][ks], acc[i][j]);
    }
}

// Q/K projections (z=0: Q scaled by 0.125, z=1: K). C layout [B,H,S,Dh] bf16.
__global__ __launch_bounds__(256) void gemm_qk(const ushort_t* __restrict__ A0,
                                               const ushort_t* __restrict__ A1,
                                               const ushort_t* __restrict__ Wq,
                                               const ushort_t* __restrict__ Wk,
                                               ushort_t* __restrict__ Qo,
                                               ushort_t* __restrict__ Ko)
{
    __shared__ ushort_t sA[128 * 64];
    __shared__ ushort_t sB[64 * 64];
    const int z = blockIdx.z;
    const ushort_t* A = z ? A1 : A0;
    const ushort_t* W = z ? Wk : Wq;
    ushort_t* C = z ? Ko : Qo;
    const float scale = z ? 1.0f : 0.125f;
    const int t = threadIdx.x, lane = t & 63, w = t >> 6;
    const int lr = lane & 15, lg = lane >> 4;
    const int wm = (w >> 1) * 64, wn = (w & 1) * 32;
    const int m0 = blockIdx.x * 128, n0 = blockIdx.y * 64;

    f32x4 acc[4][2];
    f32x4 zero = {0.f, 0.f, 0.f, 0.f};
#pragma unroll
    for (int i = 0; i < 4; i++)
#pragma unroll
        for (int j = 0; j < 2; j++) acc[i][j] = zero;
    gemm_core(A, W, m0, n0, t, sA, sB, acc);

#pragma unroll
    for (int i = 0; i < 4; i++)
#pragma unroll
        for (int j = 0; j < 2; j++)
#pragma unroll
            for (int r = 0; r < 4; r++) {
                int m = m0 + wm + i * 16 + 4 * lg + r;   // token (b*S+s)
                int n = n0 + wn + j * 16 + lr;           // feature
                int b = m >> 11, s = m & 2047;
                int h = n >> 6, dh = n & 63;
                C[(((size_t)(b * NH + h)) * SEQ + s) * DH + dh] = f2bf(acc[i][j][r] * scale);
            }
}

// V projection -> transposed output VT [B,H,Dh,S] bf16 (r-packed us4 stores)
__global__ __launch_bounds__(256) void gemm_v(const ushort_t* __restrict__ A,
                                              const ushort_t* __restrict__ W,
                                              ushort_t* __restrict__ VT)
{
    __shared__ ushort_t sA[128 * 64];
    __shared__ ushort_t sB[64 * 64];
    const int t = threadIdx.x, lane = t & 63, w = t >> 6;
    const int lr = lane & 15, lg = lane >> 4;
    const int wm = (w >> 1) * 64, wn = (w & 1) * 32;
    const int m0 = blockIdx.x * 128, n0 = blockIdx.y * 64;

    f32x4 acc[4][2];
    f32x4 zero = {0.f, 0.f, 0.f, 0.f};
#pragma unroll
    for (int i = 0; i < 4; i++)
#pragma unroll
        for (int j = 0; j < 2; j++) acc[i][j] = zero;
    gemm_core(A, W, m0, n0, t, sA, sB, acc);

#pragma unroll
    for (int i = 0; i < 4; i++)
#pragma unroll
        for (int j = 0; j < 2; j++) {
            int m = m0 + wm + i * 16 + 4 * lg;           // s base; r adds 0..3
            int n = n0 + wn + j * 16 + lr;
            int b = m >> 11, s = m & 2047;
            int h = n >> 6, dh = n & 63;
            us4 o;
#pragma unroll
            for (int r = 0; r < 4; r++) o[r] = f2bf(acc[i][j][r]);
            *(us4*)&VT[(((size_t)(b * NH + h)) * DH + dh) * SEQ + s] = o;
        }
}

// output projection: A bf16 [4096][1024] @ W0^T -> fp32 [4096][1024]
__global__ __launch_bounds__(256) void gemm_o(const ushort_t* __restrict__ A,
                                              const ushort_t* __restrict__ W,
                                              float* __restrict__ C)
{
    __shared__ ushort_t sA[128 * 64];
    __shared__ ushort_t sB[64 * 64];
    const int t = threadIdx.x, lane = t & 63, w = t >> 6;
    const int lr = lane & 15, lg = lane >> 4;
    const int wm = (w >> 1) * 64, wn = (w & 1) * 32;
    const int m0 = blockIdx.x * 128, n0 = blockIdx.y * 64;

    f32x4 acc[4][2];
    f32x4 zero = {0.f, 0.f, 0.f, 0.f};
#pragma unroll
    for (int i = 0; i < 4; i++)
#pragma unroll
        for (int j = 0; j < 2; j++) acc[i][j] = zero;
    gemm_core(A, W, m0, n0, t, sA, sB, acc);

#pragma unroll
    for (int i = 0; i < 4; i++)
#pragma unroll
        for (int j = 0; j < 2; j++)
#pragma unroll
            for (int r = 0; r < 4; r++) {
                int m = m0 + wm + i * 16 + 4 * lg + r;
                int n = n0 + wn + j * 16 + lr;
                C[(size_t)m * D_MODEL + n] = acc[i][j][r];
            }
}

// ---------------------------------------------------------------------------
// Flash attention: 4 waves x 32 q-rows (block = 128 q x head). K and V^T
// staged to LDS via global_load_lds with PRE-SWIZZLED source (rule #21):
// LDS chunk (row, c) holds global chunk (row, c^(row&7)); ds_read applies
// the same XOR -> conflict-free. Q pre-scaled; l via ones-MFMA; defer-max.
// XCD swizzle: blocks of one head land on one XCD (L2 locality).
// ---------------------------------------------------------------------------
__global__ __launch_bounds__(256) void attn_fwd(const ushort_t* __restrict__ Q,
                                                const ushort_t* __restrict__ K,
                                                const ushort_t* __restrict__ VT,
                                                const float* __restrict__ mask,
                                                const int* __restrict__ flags,
                                                ushort_t* __restrict__ O)
{
    __shared__ ushort_t sK[64 * 64];
    __shared__ ushort_t sVT[64 * 64];       // rows = d, cols = kv
    __shared__ ushort_t sP[4][32 * 64];     // per-wave [32 q][64 kv]

    const int t = threadIdx.x, lane = t & 63, w = t >> 6;
    const int lr = lane & 15, lg = lane >> 4;
    // XCD-aware id -> (qt, bh): xcd = id&7 owns heads 4*xcd..+3, all 16 q-tiles
    const int id = blockIdx.x;
    const int bh = (id & 7) * 4 + ((id >> 3) >> 4);
    const int qt = (id >> 3) & 15;
    const int b = bh >> 4, h = bh & 15;
    const int q0 = qt * 128 + w * 32;

    // mask-tile flags for this 128-row q block: OR of two 64-row flag rows
    unsigned long long blt =
        __ballot(flags[(qt * 2 + (lane >> 5)) * 32 + (lane & 31)] != 0);
    const unsigned int fl = (unsigned int)(blt | (blt >> 32));

    // Q fragments [fm][ks] (row = q0+fm*16+lr, k-contiguous)
    us8 qf[2][2];
#pragma unroll
    for (int fm = 0; fm < 2; fm++)
#pragma unroll
        for (int ks = 0; ks < 2; ks++)
            qf[fm][ks] = *(const us8*)(Q + ((size_t)bh * SEQ + q0 + fm * 16 + lr) * DH
                                       + ks * 32 + 8 * lg);

    f32x4 zero = {0.f, 0.f, 0.f, 0.f};
    f32x4 acc_o[2][4], acc_l[2];
#pragma unroll
    for (int fm = 0; fm < 2; fm++) {
        acc_l[fm] = zero;
#pragma unroll
        for (int fd = 0; fd < 4; fd++) acc_o[fm][fd] = zero;
    }
    float m_run[2][4];
#pragma unroll
    for (int fm = 0; fm < 2; fm++)
#pragma unroll
        for (int r = 0; r < 4; r++) m_run[fm][r] = -1e30f;

    const ushort_t* Kb = K + (size_t)bh * SEQ * DH;
    const ushort_t* Vb = VT + (size_t)bh * DH * SEQ;
    char* cK = (char*)sK;
    char* cV = (char*)sVT;
    char* cP = (char*)sP + w * 4096;

    us8 ones;
#pragma unroll
    for (int i = 0; i < 8; i++) ones[i] = 0x3F80;   // bf16 1.0

    for (int kvt = 0; kvt < SEQ / 64; ++kvt) {
        __syncthreads();
        // ---- stage K [64][64] (2 gload16 rounds, pre-swizzled source) ----
#pragma unroll
        for (int r = 0; r < 2; r++) {
            int j0 = r * 256 + w * 64;
            int j = j0 + lane;
            int row = j >> 3, cc = (j & 7) ^ (row & 7);
            gload16(Kb + (size_t)(kvt * 64 + row) * DH + cc * 8, &sK[j0 * 8]);
        }
        // ---- stage V^T [64 d][64 kv] (rows contiguous in VT) ----
#pragma unroll
        for (int r = 0; r < 2; r++) {
            int j0 = r * 256 + w * 64;
            int j = j0 + lane;
            int row = j >> 3, cc = (j & 7) ^ (row & 7);
            gload16(Vb + (size_t)row * SEQ + kvt * 64 + cc * 8, &sVT[j0 * 8]);
        }
        __syncthreads();

        // ---- scores = Q K^T (Q pre-scaled) ----
        f32x4 sacc[2][4];
#pragma unroll
        for (int fm = 0; fm < 2; fm++)
#pragma unroll
            for (int fn = 0; fn < 4; fn++) sacc[fm][fn] = zero;
#pragma unroll
        for (int fn = 0; fn < 4; fn++) {
            int rowk = fn * 16 + lr;
            int swz = (rowk & 7) << 4, base = rowk * 128;
#pragma unroll
            for (int ks = 0; ks < 2; ks++) {
                us8 kf = *(const us8*)(cK + ((base + (ks * 32 + 8 * lg) * 2) ^ swz));
#pragma unroll
                for (int fm = 0; fm < 2; fm++)
                    sacc[fm][fn] = mfma16(qf[fm][ks], kf, sacc[fm][fn]);
            }
        }

        // ---- additive mask (skipped when tile all-zero) ----
        if ((fl >> kvt) & 1u) {
#pragma unroll
            for (int fm = 0; fm < 2; fm++)
#pragma unroll
                for (int r = 0; r < 4; r++) {
                    int q = q0 + fm * 16 + 4 * lg + r;
#pragma unroll
                    for (int fn = 0; fn < 4; fn++)
                        sacc[fm][fn][r] += mask[(size_t)q * SEQ + kvt * 64 + fn * 16 + lr];
                }
        }

        // ---- row max (16-lane reduce) + defer-max rescale (THR=8) ----
        float mx[2][4];
#pragma unroll
        for (int fm = 0; fm < 2; fm++)
#pragma unroll
            for (int r = 0; r < 4; r++) {
                float m = fmaxf(fmaxf(sacc[fm][0][r], sacc[fm][1][r]),
                                fmaxf(sacc[fm][2][r], sacc[fm][3][r]));
#pragma unroll
                for (int off = 1; off < 16; off <<= 1) m = fmaxf(m, __shfl_xor(m, off));
                mx[fm][r] = m;
            }
        bool need = false;
#pragma unroll
        for (int fm = 0; fm < 2; fm++)
#pragma unroll
            for (int r = 0; r < 4; r++) need |= (mx[fm][r] > m_run[fm][r] + 8.f);
        if (__any((int)need)) {
#pragma unroll
            for (int fm = 0; fm < 2; fm++)
#pragma unroll
                for (int r = 0; r < 4; r++) {
                    float mn = fmaxf(m_run[fm][r], mx[fm][r]);
                    float sc = __expf(m_run[fm][r] - mn);
                    m_run[fm][r] = mn;
                    acc_l[fm][r] *= sc;
#pragma unroll
                    for (int fd = 0; fd < 4; fd++) acc_o[fm][fd][r] *= sc;
                }
        }

        // ---- P = exp(S - m) -> per-wave LDS (swizzled bf16) ----
#pragma unroll
        for (int fm = 0; fm < 2; fm++)
#pragma unroll
            for (int r = 0; r < 4; r++) {
                int qr = fm * 16 + 4 * lg + r;
                int swz = (qr & 7) << 4, base = qr * 128;
#pragma unroll
                for (int fn = 0; fn < 4; fn++) {
                    float p = __expf(sacc[fm][fn][r] - m_run[fm][r]);
                    *(ushort_t*)(cP + ((base + (fn * 16 + lr) * 2) ^ swz)) = f2bf(p);
                }
            }

        // ---- O += P @ V ; l += P @ 1 ----
#pragma unroll
        for (int ks = 0; ks < 2; ks++) {
            us8 pf[2];
#pragma unroll
            for (int fm = 0; fm < 2; fm++) {
                int rowp = fm * 16 + lr;
                pf[fm] = *(const us8*)(cP + ((rowp * 128 + (ks * 32 + 8 * lg) * 2)
                                             ^ ((rowp & 7) << 4)));
            }
#pragma unroll
            for (int fm = 0; fm < 2; fm++)
                acc_l[fm] = mfma16(pf[fm], ones, acc_l[fm]);
#pragma unroll
            for (int fd = 0; fd < 4; fd++) {
                int rowv = fd * 16 + lr;
                us8 vf = *(const us8*)(cV + ((rowv * 128 + (ks * 32 + 8 * lg) * 2)
                                             ^ ((rowv & 7) << 4)));
#pragma unroll
                for (int fm = 0; fm < 2; fm++)
                    acc_o[fm][fd] = mfma16(pf[fm], vf, acc_o[fm][fd]);
            }
        }
    }

    // ---- normalize + write [B*S][D] bf16 ----
#pragma unroll
    for (int fm = 0; fm < 2; fm++)
#pragma unroll
        for (int r = 0; r < 4; r++) {
            float inv = 1.f / acc_l[fm][r];
            int q = q0 + fm * 16 + 4 * lg + r;
#pragma unroll
            for (int fd = 0; fd < 4; fd++)
                O[((size_t)(b * SEQ + q)) * D_MODEL + h * DH + fd * 16 + lr] =
                    f2bf(acc_o[fm][fd][r] * inv);
        }
}

// ---------------------------------------------------------------------------
extern "C" void kernel_launch(void* const* d_in, const int* in_sizes, int n_in,
                              void* d_out, int out_size, void* d_ws, size_t ws_size,
                              hipStream_t stream)
{
    const float* qx   = (const float*)d_in[0];
    const float* kx   = (const float*)d_in[1];
    const float* vx   = (const float*)d_in[2];
    const float* mask = (const float*)d_in[3];
    const float* wq   = (const float*)d_in[4];
    const float* wk   = (const float*)d_in[5];
    const float* wv   = (const float*)d_in[6];
    const float* w0   = (const float*)d_in[7];
    float* out = (float*)d_out;

    char* ws = (char*)d_ws;
    const size_t MB = 1024 * 1024;
    ushort_t* A0 = (ushort_t*)(ws);                 // 8 MB (qx bf16, then vx bf16)
    ushort_t* A1 = (ushort_t*)(ws + 8 * MB);        // 8 MB (kx bf16, then AO)
    ushort_t* Wq = (ushort_t*)(ws + 16 * MB);       // 2 MB each
    ushort_t* Wk = (ushort_t*)(ws + 18 * MB);
    ushort_t* Wv = (ushort_t*)(ws + 20 * MB);
    ushort_t* W0 = (ushort_t*)(ws + 22 * MB);
    ushort_t* VT = (ushort_t*)(ws + 24 * MB);       // [B,H,Dh,S] bf16, 8 MB
    int* flags   = (int*)(ws + 32 * MB);            // [32][32]
    ushort_t* AO = A1;                              // attn out reuses A1
    // Q and K (bf16, [B,H,S,Dh]) live in d_out until attn consumes them
    ushort_t* Qb = (ushort_t*)d_out;
    ushort_t* Kb = (ushort_t*)d_out + 4 * MB;       // +8 MB bytes

    hipMemsetAsync(flags, 0, 32 * 32 * sizeof(int), stream);
    mask_flags<<<dim3(32, 32), 256, 0, stream>>>(mask, flags);

    // weights fp32 -> bf16 (one fused launch)
    conv_multi<<<dim3(256, 1, 4), 256, 0, stream>>>(wq, Wq, wk, Wk, wv, Wv, w0, W0, 262144);
    // qx, kx fp32 -> bf16
    conv_multi<<<dim3(1024, 1, 2), 256, 0, stream>>>(qx, A0, kx, A1, qx, A0, qx, A0, 1048576);

    gemm_qk<<<dim3(32, 16, 2), 256, 0, stream>>>(A0, A1, Wq, Wk, Qb, Kb);

    // vx fp32 -> bf16 (A0 free after gemm_qk)
    conv_multi<<<dim3(1024, 1, 1), 256, 0, stream>>>(vx, A0, vx, A0, vx, A0, vx, A0, 1048576);
    gemm_v<<<dim3(32, 16), 256, 0, stream>>>(A0, Wv, VT);

    attn_fwd<<<512, 256, 0, stream>>>(Qb, Kb, VT, mask, flags, AO);

    gemm_o<<<dim3(32, 16), 256, 0, stream>>>(AO, W0, out);
}

// Round 5
// 176.387 us; speedup vs baseline: 2.1631x; 1.0753x over previous
//
#include <hip/hip_runtime.h>
#include <hip/hip_bf16.h>
#include <stdint.h>

#define D_MODEL 1024
#define NH 16
#define DH 64
#define SEQ 2048
#define MROWS 4096   // B*S
#define LOG2E 1.44269504088896340736f

typedef unsigned short ushort_t;
typedef __attribute__((ext_vector_type(4))) float f32x4;
typedef __attribute__((ext_vector_type(4))) unsigned short us4;
typedef __attribute__((ext_vector_type(8))) unsigned short us8;
typedef __attribute__((ext_vector_type(8))) __bf16 bf16x8;

__device__ __forceinline__ f32x4 mfma16(us8 a, us8 b, f32x4 c) {
    return __builtin_amdgcn_mfma_f32_16x16x32_bf16(
        __builtin_bit_cast(bf16x8, a), __builtin_bit_cast(bf16x8, b), c, 0, 0, 0);
}

// fp32 -> bf16 round-to-nearest-even (finite inputs)
__device__ __forceinline__ ushort_t f2bf(float f) {
    union { float f; uint32_t u; } v; v.f = f;
    uint32_t r = v.u + 0x7fffu + ((v.u >> 16) & 1u);
    return (ushort_t)(r >> 16);
}

// native exp2 (softmax runs in log2 domain; scale folded into Q projection)
__device__ __forceinline__ float exp2_fast(float x) {
#if __has_builtin(__builtin_amdgcn_exp2f)
    return __builtin_amdgcn_exp2f(x);
#else
    float r; asm("v_exp_f32 %0, %1" : "=v"(r) : "v"(x)); return r;
#endif
}

// async global->LDS, 16B per lane; LDS base wave-uniform, lane i at base+i*16
__device__ __forceinline__ void gload16(const void* g, void* l) {
    __builtin_amdgcn_global_load_lds(
        (const __attribute__((address_space(1))) void*)g,
        (__attribute__((address_space(3))) void*)l, 16, 0, 0);
}

// ---------------------------------------------------------------------------
// fused fp32 -> bf16 convert; blockIdx.z picks (src,dst) pair; n4 = float4 count
// ---------------------------------------------------------------------------
__global__ __launch_bounds__(256) void conv_multi(
    const float* __restrict__ s0, ushort_t* __restrict__ d0,
    const float* __restrict__ s1, ushort_t* __restrict__ d1,
    const float* __restrict__ s2, ushort_t* __restrict__ d2,
    const float* __restrict__ s3, ushort_t* __restrict__ d3, int n4)
{
    int z = blockIdx.z;
    const float* s = z == 0 ? s0 : z == 1 ? s1 : z == 2 ? s2 : s3;
    ushort_t* d    = z == 0 ? d0 : z == 1 ? d1 : z == 2 ? d2 : d3;
    int i = blockIdx.x * 256 + threadIdx.x;
    int stride = gridDim.x * 256;
    for (; i < n4; i += stride) {
        float4 v = ((const float4*)s)[i];
        us4 o;
        o[0] = f2bf(v.x); o[1] = f2bf(v.y); o[2] = f2bf(v.z); o[3] = f2bf(v.w);
        ((us4*)d)[i] = o;
    }
}

// ---------------------------------------------------------------------------
// mask tile flags at 64x64 granularity
// ---------------------------------------------------------------------------
__global__ __launch_bounds__(256) void mask_flags(const float* __restrict__ mask,
                                                  int* __restrict__ flags)
{
    int qt = blockIdx.x, kt = blockIdx.y;
    int t = threadIdx.x;
    bool nz = false;
#pragma unroll
    for (int i = 0; i < 4; i++) {
        int idx = t + i * 256;               // 1024 float4: 64 rows x 16
        int row = idx >> 4, c4 = (idx & 15) * 4;
        float4 v = *(const float4*)(mask + (size_t)(qt * 64 + row) * SEQ + kt * 64 + c4);
        nz |= (v.x != 0.f) | (v.y != 0.f) | (v.z != 0.f) | (v.w != 0.f);
    }
    if (__any((int)nz) && (t & 63) == 0) atomicOr(&flags[qt * 32 + kt], 1);
}

// ---------------------------------------------------------------------------
// shared GEMM core: C(acc) = A[4096][1024] @ W^T, BM=128 BN=64 BK=64,
// global_load_lds 16B staging (m97 structure)
// ---------------------------------------------------------------------------
__device__ __forceinline__ void gemm_core(const ushort_t* __restrict__ A,
                                          const ushort_t* __restrict__ B,
                                          int m0, int n0, int t,
                                          ushort_t* sA, ushort_t* sB,
                                          f32x4 acc[4][2])
{
    const int lane = t & 63, w = t >> 6;
    const int lr = lane & 15, lg = lane >> 4;
    const int wm = (w >> 1) * 64, wn = (w & 1) * 32;

    for (int k0 = 0; k0 < D_MODEL; k0 += 64) {
        __syncthreads();
#pragma unroll
        for (int r = 0; r < 4; r++) {
            int chunk = r * 256 + t;                   // 1024 chunks of 8 bf16
            int row = chunk >> 3, c8 = (chunk & 7) * 8;
            gload16(A + (size_t)(m0 + row) * D_MODEL + k0 + c8,
                    &sA[(r * 256 + w * 64) * 8]);
        }
#pragma unroll
        for (int r = 0; r < 2; r++) {
            int chunk = r * 256 + t;
            int row = chunk >> 3, c8 = (chunk & 7) * 8;
            gload16(B + (size_t)(n0 + row) * D_MODEL + k0 + c8,
                    &sB[(r * 256 + w * 64) * 8]);
        }
        __syncthreads();

        us8 af[4][2], bfr[2][2];
#pragma unroll
        for (int i = 0; i < 4; i++)
#pragma unroll
            for (int ks = 0; ks < 2; ks++)
                af[i][ks] = *(const us8*)&sA[(wm + i * 16 + lr) * 64 + ks * 32 + 8 * lg];
#pragma unroll
        for (int j = 0; j < 2; j++)
#pragma unroll
            for (int ks = 0; ks < 2; ks++)
                bfr[j][ks] = *(const us8*)&sB[(wn + j * 16 + lr) * 64 + ks * 32 + 8 * lg];
#pragma unroll
        for (int i = 0; i < 4; i++)
#pragma unroll
            for (int j = 0; j < 2; j++)
#pragma unroll
                for (int ks = 0; ks < 2; ks++)
                    acc[i][j] = mfma16(af[i][ks], bfr[j][ks], acc[i][j]);
    }
}

// Q/K projections (z=0: Q scaled by 0.125*log2e, z=1: K). C layout [B,H,S,Dh] bf16.
__global__ __launch_bounds__(256) void gemm_qk(const ushort_t* __restrict__ A0,
                                               const ushort_t* __restrict__ A1,
                                               const ushort_t* __restrict__ Wq,
                                               const ushort_t* __restrict__ Wk,
                                               ushort_t* __restrict__ Qo,
                                               ushort_t* __restrict__ Ko)
{
    __shared__ ushort_t sA[128 * 64];
    __shared__ ushort_t sB[64 * 64];
    const int z = blockIdx.z;
    const ushort_t* A = z ? A1 : A0;
    const ushort_t* W = z ? Wk : Wq;
    ushort_t* C = z ? Ko : Qo;
    const float scale = z ? 1.0f : 0.125f * LOG2E;   // scores in log2 units
    const int t = threadIdx.x, lane = t & 63, w = t >> 6;
    const int lr = lane & 15, lg = lane >> 4;
    const int wm = (w >> 1) * 64, wn = (w & 1) * 32;
    const int m0 = blockIdx.x * 128, n0 = blockIdx.y * 64;

    f32x4 acc[4][2];
    f32x4 zero = {0.f, 0.f, 0.f, 0.f};
#pragma unroll
    for (int i = 0; i < 4; i++)
#pragma unroll
        for (int j = 0; j < 2; j++) acc[i][j] = zero;
    gemm_core(A, W, m0, n0, t, sA, sB, acc);

#pragma unroll
    for (int i = 0; i < 4; i++)
#pragma unroll
        for (int j = 0; j < 2; j++)
#pragma unroll
            for (int r = 0; r < 4; r++) {
                int m = m0 + wm + i * 16 + 4 * lg + r;   // token (b*S+s)
                int n = n0 + wn + j * 16 + lr;           // feature
                int b = m >> 11, s = m & 2047;
                int h = n >> 6, dh = n & 63;
                C[(((size_t)(b * NH + h)) * SEQ + s) * DH + dh] = f2bf(acc[i][j][r] * scale);
            }
}

// V projection -> transposed output VT [B,H,Dh,S] bf16 (r-packed us4 stores)
__global__ __launch_bounds__(256) void gemm_v(const ushort_t* __restrict__ A,
                                              const ushort_t* __restrict__ W,
                                              ushort_t* __restrict__ VT)
{
    __shared__ ushort_t sA[128 * 64];
    __shared__ ushort_t sB[64 * 64];
    const int t = threadIdx.x, lane = t & 63, w = t >> 6;
    const int lr = lane & 15, lg = lane >> 4;
    const int wm = (w >> 1) * 64, wn = (w & 1) * 32;
    const int m0 = blockIdx.x * 128, n0 = blockIdx.y * 64;

    f32x4 acc[4][2];
    f32x4 zero = {0.f, 0.f, 0.f, 0.f};
#pragma unroll
    for (int i = 0; i < 4; i++)
#pragma unroll
        for (int j = 0; j < 2; j++) acc[i][j] = zero;
    gemm_core(A, W, m0, n0, t, sA, sB, acc);

#pragma unroll
    for (int i = 0; i < 4; i++)
#pragma unroll
        for (int j = 0; j < 2; j++) {
            int m = m0 + wm + i * 16 + 4 * lg;           // s base; r adds 0..3
            int n = n0 + wn + j * 16 + lr;
            int b = m >> 11, s = m & 2047;
            int h = n >> 6, dh = n & 63;
            us4 o;
#pragma unroll
            for (int r = 0; r < 4; r++) o[r] = f2bf(acc[i][j][r]);
            *(us4*)&VT[(((size_t)(b * NH + h)) * DH + dh) * SEQ + s] = o;
        }
}

// output projection: A bf16 [4096][1024] @ W0^T -> fp32 [4096][1024]
__global__ __launch_bounds__(256) void gemm_o(const ushort_t* __restrict__ A,
                                              const ushort_t* __restrict__ W,
                                              float* __restrict__ C)
{
    __shared__ ushort_t sA[128 * 64];
    __shared__ ushort_t sB[64 * 64];
    const int t = threadIdx.x, lane = t & 63, w = t >> 6;
    const int lr = lane & 15, lg = lane >> 4;
    const int wm = (w >> 1) * 64, wn = (w & 1) * 32;
    const int m0 = blockIdx.x * 128, n0 = blockIdx.y * 64;

    f32x4 acc[4][2];
    f32x4 zero = {0.f, 0.f, 0.f, 0.f};
#pragma unroll
    for (int i = 0; i < 4; i++)
#pragma unroll
        for (int j = 0; j < 2; j++) acc[i][j] = zero;
    gemm_core(A, W, m0, n0, t, sA, sB, acc);

#pragma unroll
    for (int i = 0; i < 4; i++)
#pragma unroll
        for (int j = 0; j < 2; j++)
#pragma unroll
            for (int r = 0; r < 4; r++) {
                int m = m0 + wm + i * 16 + 4 * lg + r;
                int n = n0 + wn + j * 16 + lr;
                C[(size_t)m * D_MODEL + n] = acc[i][j][r];
            }
}

// ---------------------------------------------------------------------------
// Flash attention: 8 waves x 16 q-rows (block = 128 q x head), 512 threads.
// Double-buffered K/V^T staging (T3-minimum 2-phase: stage(t+1) issued before
// compute(t), one __syncthreads per tile drains it). Pre-swizzled gload source
// + XOR on ds_read (rule #21). Scores in log2 domain (v_exp direct).
// l via ones-MFMA; defer-max THR=8*log2e. XCD swizzle for L2 locality.
// ---------------------------------------------------------------------------
__global__ __launch_bounds__(512, 4) void attn_fwd(const ushort_t* __restrict__ Q,
                                                   const ushort_t* __restrict__ K,
                                                   const ushort_t* __restrict__ VT,
                                                   const float* __restrict__ mask,
                                                   const int* __restrict__ flags,
                                                   ushort_t* __restrict__ O)
{
    __shared__ ushort_t sK[2][64 * 64];
    __shared__ ushort_t sVT[2][64 * 64];    // rows = d, cols = kv
    __shared__ ushort_t sP[8][16 * 64];     // per-wave [16 q][64 kv]

    const int t = threadIdx.x, lane = t & 63, w = t >> 6;
    const int lr = lane & 15, lg = lane >> 4;
    // XCD-aware id -> (qt, bh): xcd = id&7 owns heads 4*xcd..+3, all 16 q-tiles
    const int id = blockIdx.x;
    const int bh = (id & 7) * 4 + ((id >> 3) >> 4);
    const int qt = (id >> 3) & 15;
    const int b = bh >> 4, h = bh & 15;
    const int q0 = qt * 128 + w * 16;

    // mask-tile flags for this 128-row q block: OR of two 64-row flag rows
    unsigned long long blt =
        __ballot(flags[(qt * 2 + (lane >> 5)) * 32 + (lane & 31)] != 0);
    const unsigned int fl = (unsigned int)(blt | (blt >> 32));

    // Q fragments (row = q0+lr, k-contiguous)
    us8 qf[2];
#pragma unroll
    for (int ks = 0; ks < 2; ks++)
        qf[ks] = *(const us8*)(Q + ((size_t)bh * SEQ + q0 + lr) * DH + ks * 32 + 8 * lg);

    f32x4 zero = {0.f, 0.f, 0.f, 0.f};
    f32x4 acc_o[4], acc_l = zero;
#pragma unroll
    for (int fd = 0; fd < 4; fd++) acc_o[fd] = zero;
    float m_run[4];
#pragma unroll
    for (int r = 0; r < 4; r++) m_run[r] = -1e30f;

    const ushort_t* Kb = K + (size_t)bh * SEQ * DH;
    const ushort_t* Vb = VT + (size_t)bh * DH * SEQ;
    char* cP = (char*)sP + w * 2048;

    // staging coords (512 threads, 1 chunk each per buffer)
    const int srow = t >> 3, scc = (t & 7) ^ ((t >> 3) & 7);

    us8 ones;
#pragma unroll
    for (int i = 0; i < 8; i++) ones[i] = 0x3F80;   // bf16 1.0

    // prologue: stage tile 0 into buf 0
    gload16(Kb + (size_t)srow * DH + scc * 8, &sK[0][(w * 64) * 8]);
    gload16(Vb + (size_t)srow * SEQ + 0 + scc * 8, &sVT[0][(w * 64) * 8]);
    __syncthreads();

    for (int kvt = 0; kvt < SEQ / 64; ++kvt) {
        const int cur = kvt & 1;
        // ---- issue stage of tile kvt+1 into the other buffer ----
        if (kvt + 1 < SEQ / 64) {
            gload16(Kb + (size_t)((kvt + 1) * 64 + srow) * DH + scc * 8,
                    &sK[cur ^ 1][(w * 64) * 8]);
            gload16(Vb + (size_t)srow * SEQ + (kvt + 1) * 64 + scc * 8,
                    &sVT[cur ^ 1][(w * 64) * 8]);
        }
        char* cK = (char*)sK[cur];
        char* cV = (char*)sVT[cur];

        // ---- scores = Q K^T (log2 units) ----
        f32x4 sacc[4];
#pragma unroll
        for (int fn = 0; fn < 4; fn++) sacc[fn] = zero;
#pragma unroll
        for (int fn = 0; fn < 4; fn++) {
            int rowk = fn * 16 + lr;
            int swz = (rowk & 7) << 4, base = rowk * 128;
#pragma unroll
            for (int ks = 0; ks < 2; ks++) {
                us8 kf = *(const us8*)(cK + ((base + (ks * 32 + 8 * lg) * 2) ^ swz));
                sacc[fn] = mfma16(qf[ks], kf, sacc[fn]);
            }
        }

        // ---- additive mask (log2 scale; skipped when tile all-zero) ----
        if ((fl >> kvt) & 1u) {
#pragma unroll
            for (int r = 0; r < 4; r++) {
                int q = q0 + 4 * lg + r;
#pragma unroll
                for (int fn = 0; fn < 4; fn++)
                    sacc[fn][r] += mask[(size_t)q * SEQ + kvt * 64 + fn * 16 + lr] * LOG2E;
            }
        }

        // ---- row max (16-lane reduce) + defer-max rescale (THR=8*log2e) ----
        float mx[4];
#pragma unroll
        for (int r = 0; r < 4; r++) {
            float m = fmaxf(fmaxf(sacc[0][r], sacc[1][r]), fmaxf(sacc[2][r], sacc[3][r]));
#pragma unroll
            for (int off = 1; off < 16; off <<= 1) m = fmaxf(m, __shfl_xor(m, off));
            mx[r] = m;
        }
        bool need = (mx[0] > m_run[0] + 11.541560f) | (mx[1] > m_run[1] + 11.541560f) |
                    (mx[2] > m_run[2] + 11.541560f) | (mx[3] > m_run[3] + 11.541560f);
        if (__any((int)need)) {
#pragma unroll
            for (int r = 0; r < 4; r++) {
                float mn = fmaxf(m_run[r], mx[r]);
                float sc = exp2_fast(m_run[r] - mn);
                m_run[r] = mn;
                acc_l[r] *= sc;
#pragma unroll
                for (int fd = 0; fd < 4; fd++) acc_o[fd][r] *= sc;
            }
        }

        // ---- P = exp2(S - m) -> per-wave LDS (swizzled bf16) ----
#pragma unroll
        for (int r = 0; r < 4; r++) {
            int qr = 4 * lg + r;
            int swz = (qr & 7) << 4, base = qr * 128;
#pragma unroll
            for (int fn = 0; fn < 4; fn++) {
                float p = exp2_fast(sacc[fn][r] - m_run[r]);
                *(ushort_t*)(cP + ((base + (fn * 16 + lr) * 2) ^ swz)) = f2bf(p);
            }
        }

        // ---- O += P @ V ; l += P @ 1 ----
#pragma unroll
        for (int ks = 0; ks < 2; ks++) {
            int rowp = lr;
            us8 pf = *(const us8*)(cP + ((rowp * 128 + (ks * 32 + 8 * lg) * 2)
                                         ^ ((rowp & 7) << 4)));
            acc_l = mfma16(pf, ones, acc_l);
#pragma unroll
            for (int fd = 0; fd < 4; fd++) {
                int rowv = fd * 16 + lr;
                us8 vf = *(const us8*)(cV + ((rowv * 128 + (ks * 32 + 8 * lg) * 2)
                                             ^ ((rowv & 7) << 4)));
                acc_o[fd] = mfma16(pf, vf, acc_o[fd]);
            }
        }

        // ---- single barrier: drains stage(kvt+1) (overlapped with compute) ----
        __syncthreads();
    }

    // ---- normalize + write [B*S][D] bf16 ----
#pragma unroll
    for (int r = 0; r < 4; r++) {
        float inv = 1.f / acc_l[r];
        int q = q0 + 4 * lg + r;
#pragma unroll
        for (int fd = 0; fd < 4; fd++)
            O[((size_t)(b * SEQ + q)) * D_MODEL + h * DH + fd * 16 + lr] =
                f2bf(acc_o[fd][r] * inv);
    }
}

// ---------------------------------------------------------------------------
extern "C" void kernel_launch(void* const* d_in, const int* in_sizes, int n_in,
                              void* d_out, int out_size, void* d_ws, size_t ws_size,
                              hipStream_t stream)
{
    const float* qx   = (const float*)d_in[0];
    const float* kx   = (const float*)d_in[1];
    const float* vx   = (const float*)d_in[2];
    const float* mask = (const float*)d_in[3];
    const float* wq   = (const float*)d_in[4];
    const float* wk   = (const float*)d_in[5];
    const float* wv   = (const float*)d_in[6];
    const float* w0   = (const float*)d_in[7];
    float* out = (float*)d_out;

    char* ws = (char*)d_ws;
    const size_t MB = 1024 * 1024;
    ushort_t* A0 = (ushort_t*)(ws);                 // 8 MB (qx bf16, then vx bf16)
    ushort_t* A1 = (ushort_t*)(ws + 8 * MB);        // 8 MB (kx bf16, then AO)
    ushort_t* Wq = (ushort_t*)(ws + 16 * MB);       // 2 MB each
    ushort_t* Wk = (ushort_t*)(ws + 18 * MB);
    ushort_t* Wv = (ushort_t*)(ws + 20 * MB);
    ushort_t* W0 = (ushort_t*)(ws + 22 * MB);
    ushort_t* VT = (ushort_t*)(ws + 24 * MB);       // [B,H,Dh,S] bf16, 8 MB
    int* flags   = (int*)(ws + 32 * MB);            // [32][32]
    ushort_t* AO = A1;                              // attn out reuses A1
    // Q and K (bf16, [B,H,S,Dh]) live in d_out until attn consumes them
    ushort_t* Qb = (ushort_t*)d_out;
    ushort_t* Kb = (ushort_t*)d_out + 4 * MB;       // +8 MB bytes

    hipMemsetAsync(flags, 0, 32 * 32 * sizeof(int), stream);
    mask_flags<<<dim3(32, 32), 256, 0, stream>>>(mask, flags);

    // weights fp32 -> bf16 (one fused launch)
    conv_multi<<<dim3(256, 1, 4), 256, 0, stream>>>(wq, Wq, wk, Wk, wv, Wv, w0, W0, 262144);
    // qx, kx fp32 -> bf16
    conv_multi<<<dim3(1024, 1, 2), 256, 0, stream>>>(qx, A0, kx, A1, qx, A0, qx, A0, 1048576);

    gemm_qk<<<dim3(32, 16, 2), 256, 0, stream>>>(A0, A1, Wq, Wk, Qb, Kb);

    // vx fp32 -> bf16 (A0 free after gemm_qk)
    conv_multi<<<dim3(1024, 1, 1), 256, 0, stream>>>(vx, A0, vx, A0, vx, A0, vx, A0, 1048576);
    gemm_v<<<dim3(32, 16), 256, 0, stream>>>(A0, Wv, VT);

    attn_fwd<<<512, 512, 0, stream>>>(Qb, Kb, VT, mask, flags, AO);

    gemm_o<<<dim3(32, 16), 256, 0, stream>>>(AO, W0, out);
}

// Round 7
// 156.572 us; speedup vs baseline: 2.4369x; 1.1266x over previous
//
#include <hip/hip_runtime.h>
#include <hip/hip_bf16.h>
#include <stdint.h>

#define D_MODEL 1024
#define NH 16
#define DH 64
#define SEQ 2048
#define MROWS 4096   // B*S
#define LOG2E 1.44269504088896340736f

typedef unsigned short ushort_t;
typedef __attribute__((ext_vector_type(4))) float f32x4;
typedef __attribute__((ext_vector_type(16))) float f32x16;
typedef __attribute__((ext_vector_type(4))) unsigned short us4;
typedef __attribute__((ext_vector_type(8))) unsigned short us8;
typedef __attribute__((ext_vector_type(4))) unsigned int u32x4;
typedef __attribute__((ext_vector_type(8))) __bf16 bf16x8;

__device__ __forceinline__ f32x4 mfma16(us8 a, us8 b, f32x4 c) {
    return __builtin_amdgcn_mfma_f32_16x16x32_bf16(
        __builtin_bit_cast(bf16x8, a), __builtin_bit_cast(bf16x8, b), c, 0, 0, 0);
}
__device__ __forceinline__ f32x16 mfma32(us8 a, us8 b, f32x16 c) {
    return __builtin_amdgcn_mfma_f32_32x32x16_bf16(
        __builtin_bit_cast(bf16x8, a), __builtin_bit_cast(bf16x8, b), c, 0, 0, 0);
}

// fp32 -> bf16 round-to-nearest-even (finite inputs)
__device__ __forceinline__ ushort_t f2bf(float f) {
    union { float f; uint32_t u; } v; v.f = f;
    uint32_t r = v.u + 0x7fffu + ((v.u >> 16) & 1u);
    return (ushort_t)(r >> 16);
}

// packed f32x2 -> bf16x2 (documented: src0 -> low half)
__device__ __forceinline__ unsigned int cvtpk(float lo, float hi) {
    unsigned int r;
    asm("v_cvt_pk_bf16_f32 %0, %1, %2" : "=v"(r) : "v"(lo), "v"(hi));
    return r;
}

__device__ __forceinline__ float exp2_fast(float x) {
#if __has_builtin(__builtin_amdgcn_exp2f)
    return __builtin_amdgcn_exp2f(x);
#else
    float r; asm("v_exp_f32 %0, %1" : "=v"(r) : "v"(x)); return r;
#endif
}

// async global->LDS, 16B per lane; LDS base wave-uniform, lane i at base+i*16
__device__ __forceinline__ void gload16(const void* g, void* l) {
    __builtin_amdgcn_global_load_lds(
        (const __attribute__((address_space(1))) void*)g,
        (__attribute__((address_space(3))) void*)l, 16, 0, 0);
}

// ---------------------------------------------------------------------------
// fused fp32 -> bf16 convert; blockIdx.z picks (src,dst) pair; n4 = float4 count
// ---------------------------------------------------------------------------
__global__ __launch_bounds__(256) void conv_multi(
    const float* __restrict__ s0, ushort_t* __restrict__ d0,
    const float* __restrict__ s1, ushort_t* __restrict__ d1,
    const float* __restrict__ s2, ushort_t* __restrict__ d2,
    const float* __restrict__ s3, ushort_t* __restrict__ d3, int n4)
{
    int z = blockIdx.z;
    const float* s = z == 0 ? s0 : z == 1 ? s1 : z == 2 ? s2 : s3;
    ushort_t* d    = z == 0 ? d0 : z == 1 ? d1 : z == 2 ? d2 : d3;
    int i = blockIdx.x * 256 + threadIdx.x;
    int stride = gridDim.x * 256;
    for (; i < n4; i += stride) {
        float4 v = ((const float4*)s)[i];
        us4 o;
        o[0] = f2bf(v.x); o[1] = f2bf(v.y); o[2] = f2bf(v.z); o[3] = f2bf(v.w);
        ((us4*)d)[i] = o;
    }
}

// ---------------------------------------------------------------------------
// mask tile flags at 64x64 granularity
// ---------------------------------------------------------------------------
__global__ __launch_bounds__(256) void mask_flags(const float* __restrict__ mask,
                                                  int* __restrict__ flags)
{
    int qt = blockIdx.x, kt = blockIdx.y;
    int t = threadIdx.x;
    bool nz = false;
#pragma unroll
    for (int i = 0; i < 4; i++) {
        int idx = t + i * 256;               // 1024 float4: 64 rows x 16
        int row = idx >> 4, c4 = (idx & 15) * 4;
        float4 v = *(const float4*)(mask + (size_t)(qt * 64 + row) * SEQ + kt * 64 + c4);
        nz |= (v.x != 0.f) | (v.y != 0.f) | (v.z != 0.f) | (v.w != 0.f);
    }
    if (__any((int)nz) && (t & 63) == 0) atomicOr(&flags[qt * 32 + kt], 1);
}

// ---------------------------------------------------------------------------
// shared GEMM core: C(acc) = A[4096][1024] @ W^T, BM=128 BN=64 BK=64,
// global_load_lds 16B staging (m97 structure)
// ---------------------------------------------------------------------------
__device__ __forceinline__ void gemm_core(const ushort_t* __restrict__ A,
                                          const ushort_t* __restrict__ B,
                                          int m0, int n0, int t,
                                          ushort_t* sA, ushort_t* sB,
                                          f32x4 acc[4][2])
{
    const int lane = t & 63, w = t >> 6;
    const int lr = lane & 15, lg = lane >> 4;
    const int wm = (w >> 1) * 64, wn = (w & 1) * 32;

    for (int k0 = 0; k0 < D_MODEL; k0 += 64) {
        __syncthreads();
#pragma unroll
        for (int r = 0; r < 4; r++) {
            int chunk = r * 256 + t;                   // 1024 chunks of 8 bf16
            int row = chunk >> 3, c8 = (chunk & 7) * 8;
            gload16(A + (size_t)(m0 + row) * D_MODEL + k0 + c8,
                    &sA[(r * 256 + w * 64) * 8]);
        }
#pragma unroll
        for (int r = 0; r < 2; r++) {
            int chunk = r * 256 + t;
            int row = chunk >> 3, c8 = (chunk & 7) * 8;
            gload16(B + (size_t)(n0 + row) * D_MODEL + k0 + c8,
                    &sB[(r * 256 + w * 64) * 8]);
        }
        __syncthreads();

        us8 af[4][2], bfr[2][2];
#pragma unroll
        for (int i = 0; i < 4; i++)
#pragma unroll
            for (int ks = 0; ks < 2; ks++)
                af[i][ks] = *(const us8*)&sA[(wm + i * 16 + lr) * 64 + ks * 32 + 8 * lg];
#pragma unroll
        for (int j = 0; j < 2; j++)
#pragma unroll
            for (int ks = 0; ks < 2; ks++)
                bfr[j][ks] = *(const us8*)&sB[(wn + j * 16 + lr) * 64 + ks * 32 + 8 * lg];
#pragma unroll
        for (int i = 0; i < 4; i++)
#pragma unroll
            for (int j = 0; j < 2; j++)
#pragma unroll
                for (int ks = 0; ks < 2; ks++)
                    acc[i][j] = mfma16(af[i][ks], bfr[j][ks], acc[i][j]);
    }
}

// Q/K projections (z=0: Q scaled by 0.125*log2e, z=1: K). C layout [B,H,S,Dh] bf16.
__global__ __launch_bounds__(256) void gemm_qk(const ushort_t* __restrict__ A0,
                                               const ushort_t* __restrict__ A1,
                                               const ushort_t* __restrict__ Wq,
                                               const ushort_t* __restrict__ Wk,
                                               ushort_t* __restrict__ Qo,
                                               ushort_t* __restrict__ Ko)
{
    __shared__ ushort_t sA[128 * 64];
    __shared__ ushort_t sB[64 * 64];
    const int z = blockIdx.z;
    const ushort_t* A = z ? A1 : A0;
    const ushort_t* W = z ? Wk : Wq;
    ushort_t* C = z ? Ko : Qo;
    const float scale = z ? 1.0f : 0.125f * LOG2E;   // scores in log2 units
    const int t = threadIdx.x, lane = t & 63, w = t >> 6;
    const int lr = lane & 15, lg = lane >> 4;
    const int wm = (w >> 1) * 64, wn = (w & 1) * 32;
    const int m0 = blockIdx.x * 128, n0 = blockIdx.y * 64;

    f32x4 acc[4][2];
    f32x4 zero = {0.f, 0.f, 0.f, 0.f};
#pragma unroll
    for (int i = 0; i < 4; i++)
#pragma unroll
        for (int j = 0; j < 2; j++) acc[i][j] = zero;
    gemm_core(A, W, m0, n0, t, sA, sB, acc);

#pragma unroll
    for (int i = 0; i < 4; i++)
#pragma unroll
        for (int j = 0; j < 2; j++)
#pragma unroll
            for (int r = 0; r < 4; r++) {
                int m = m0 + wm + i * 16 + 4 * lg + r;   // token (b*S+s)
                int n = n0 + wn + j * 16 + lr;           // feature
                int b = m >> 11, s = m & 2047;
                int h = n >> 6, dh = n & 63;
                C[(((size_t)(b * NH + h)) * SEQ + s) * DH + dh] = f2bf(acc[i][j][r] * scale);
            }
}

// V projection -> transposed output VT [B,H,Dh,S] bf16 (r-packed us4 stores)
__global__ __launch_bounds__(256) void gemm_v(const ushort_t* __restrict__ A,
                                              const ushort_t* __restrict__ W,
                                              ushort_t* __restrict__ VT)
{
    __shared__ ushort_t sA[128 * 64];
    __shared__ ushort_t sB[64 * 64];
    const int t = threadIdx.x, lane = t & 63, w = t >> 6;
    const int lr = lane & 15, lg = lane >> 4;
    const int wm = (w >> 1) * 64, wn = (w & 1) * 32;
    const int m0 = blockIdx.x * 128, n0 = blockIdx.y * 64;

    f32x4 acc[4][2];
    f32x4 zero = {0.f, 0.f, 0.f, 0.f};
#pragma unroll
    for (int i = 0; i < 4; i++)
#pragma unroll
        for (int j = 0; j < 2; j++) acc[i][j] = zero;
    gemm_core(A, W, m0, n0, t, sA, sB, acc);

#pragma unroll
    for (int i = 0; i < 4; i++)
#pragma unroll
        for (int j = 0; j < 2; j++) {
            int m = m0 + wm + i * 16 + 4 * lg;           // s base; r adds 0..3
            int n = n0 + wn + j * 16 + lr;
            int b = m >> 11, s = m & 2047;
            int h = n >> 6, dh = n & 63;
            us4 o;
#pragma unroll
            for (int r = 0; r < 4; r++) o[r] = f2bf(acc[i][j][r]);
            *(us4*)&VT[(((size_t)(b * NH + h)) * DH + dh) * SEQ + s] = o;
        }
}

// output projection: A bf16 [4096][1024] @ W0^T -> fp32 [4096][1024]
__global__ __launch_bounds__(256) void gemm_o(const ushort_t* __restrict__ A,
                                              const ushort_t* __restrict__ W,
                                              float* __restrict__ C)
{
    __shared__ ushort_t sA[128 * 64];
    __shared__ ushort_t sB[64 * 64];
    const int t = threadIdx.x, lane = t & 63, w = t >> 6;
    const int lr = lane & 15, lg = lane >> 4;
    const int wm = (w >> 1) * 64, wn = (w & 1) * 32;
    const int m0 = blockIdx.x * 128, n0 = blockIdx.y * 64;

    f32x4 acc[4][2];
    f32x4 zero = {0.f, 0.f, 0.f, 0.f};
#pragma unroll
    for (int i = 0; i < 4; i++)
#pragma unroll
        for (int j = 0; j < 2; j++) acc[i][j] = zero;
    gemm_core(A, W, m0, n0, t, sA, sB, acc);

#pragma unroll
    for (int i = 0; i < 4; i++)
#pragma unroll
        for (int j = 0; j < 2; j++)
#pragma unroll
            for (int r = 0; r < 4; r++) {
                int m = m0 + wm + i * 16 + 4 * lg + r;
                int n = n0 + wn + j * 16 + lr;
                C[(size_t)m * D_MODEL + n] = acc[i][j][r];
            }
}

// ---------------------------------------------------------------------------
// Flash attention, swapped-operand 32x32x16 form:
//   S = mfma32(K, Q) -> S[kcol][q], q = lane&31  => per-lane scalar softmax
//   P in registers: cvt_pk pairs + __shfl_xor(32) + select assemble PV B-frags
//   (guaranteed-semantics replacement for permlane32_swap; same data movement)
//   O = mfma32(V, P) -> O[d][q]
// 4 waves x 32 q rows (block = 128 q x head), dbuf K/V^T staging via
// global_load_lds with pre-swizzled source (rule #21). XCD swizzle.
// C/D layout (HW-verified): col=lane&31, row=(r&3)+8*(r>>2)+4*(lane>>5).
// P-frag needs (derived): lh=0 words [W0,W1,X2,X3], lh=1 words [X2',X3',W2,W3]
// where Wi = own cvtpk pair i, Xi = other half's Wi.
// ---------------------------------------------------------------------------
__global__ __launch_bounds__(256, 2) void attn_fwd(const ushort_t* __restrict__ Q,
                                                   const ushort_t* __restrict__ K,
                                                   const ushort_t* __restrict__ VT,
                                                   const float* __restrict__ mask,
                                                   const int* __restrict__ flags,
                                                   ushort_t* __restrict__ O)
{
    __shared__ ushort_t sK[2][64 * 64];
    __shared__ ushort_t sVT[2][64 * 64];    // rows = d, cols = kv

    const int t = threadIdx.x, lane = t & 63, w = t >> 6;
    const int l31 = lane & 31, lh = lane >> 5;
    const int id = blockIdx.x;
    const int bh = (id & 7) * 4 + ((id >> 3) >> 4);   // XCD-contiguous heads
    const int qt = (id >> 3) & 15;
    const int b = bh >> 4, h = bh & 15;
    const int q = qt * 128 + w * 32 + l31;   // lane's q row

    // mask-tile flags for this 128-row q block (2 flag rows ORed)
    unsigned long long blt = __ballot(flags[(qt * 2 + lh) * 32 + l31] != 0);
    const unsigned int fl = (unsigned int)(blt | (blt >> 32));

    // Q fragments: B-operand rows = q, k(d)-slots 16*ks + 8*lh + e
    us8 qfr[4];
#pragma unroll
    for (int ks = 0; ks < 4; ks++)
        qfr[ks] = *(const us8*)(Q + ((size_t)bh * SEQ + q) * DH + ks * 16 + 8 * lh);

    f32x16 acc_o[2];
#pragma unroll
    for (int d = 0; d < 2; d++)
#pragma unroll
        for (int r = 0; r < 16; r++) acc_o[d][r] = 0.f;
    float acc_l = 0.f, m_run = -1e30f;

    const ushort_t* Kb = K + (size_t)bh * SEQ * DH;
    const ushort_t* Vb = VT + (size_t)bh * DH * SEQ;

    // staging: 256 threads x 2 chunks per tensor per tile
#define STAGE(kvt_, buf_)                                                     \
    {                                                                         \
        _Pragma("unroll")                                                     \
        for (int r = 0; r < 2; r++) {                                         \
            int j = r * 256 + t;                                              \
            int row = j >> 3, cc = (j & 7) ^ (row & 7);                       \
            gload16(Kb + (size_t)((kvt_) * 64 + row) * DH + cc * 8,           \
                    &sK[buf_][(r * 256 + w * 64) * 8]);                       \
        }                                                                     \
        _Pragma("unroll")                                                     \
        for (int r = 0; r < 2; r++) {                                         \
            int j = r * 256 + t;                                              \
            int row = j >> 3, cc = (j & 7) ^ (row & 7);                       \
            gload16(Vb + (size_t)row * SEQ + (kvt_) * 64 + cc * 8,            \
                    &sVT[buf_][(r * 256 + w * 64) * 8]);                      \
        }                                                                     \
    }

    STAGE(0, 0);
    __syncthreads();

    for (int kvt = 0; kvt < SEQ / 64; ++kvt) {
        const int cur = kvt & 1;
        if (kvt + 1 < SEQ / 64) STAGE(kvt + 1, cur ^ 1);

        const char* cK = (const char*)sK[cur];
        const char* cV = (const char*)sVT[cur];

        // ---- S = K Q^T: sacc[kb][r] = S[kcol=kb*32+crow(r,lh)][q] ----
        f32x16 sacc[2];
#pragma unroll
        for (int kb = 0; kb < 2; kb++)
#pragma unroll
            for (int r = 0; r < 16; r++) sacc[kb][r] = 0.f;
#pragma unroll
        for (int ks = 0; ks < 4; ks++)
#pragma unroll
            for (int kb = 0; kb < 2; kb++) {
                int row = kb * 32 + l31;
                int by = (row * 128 + (ks * 16 + 8 * lh) * 2) ^ ((row & 7) << 4);
                us8 kf = *(const us8*)(cK + by);
                sacc[kb] = mfma32(kf, qfr[ks], sacc[kb]);
            }

        // ---- additive mask (log2; skipped when tile all-zero) ----
        if ((fl >> kvt) & 1u) {
#pragma unroll
            for (int kb = 0; kb < 2; kb++)
#pragma unroll
                for (int r = 0; r < 16; r++) {
                    int kcol = kb * 32 + (r & 3) + 8 * (r >> 2) + 4 * lh;
                    sacc[kb][r] += mask[(size_t)q * SEQ + kvt * 64 + kcol] * LOG2E;
                }
        }

        // ---- row max: in-lane tree + 1 cross-half shfl ----
        float mx = sacc[0][0];
#pragma unroll
        for (int kb = 0; kb < 2; kb++)
#pragma unroll
            for (int r = 0; r < 16; r++) mx = fmaxf(mx, sacc[kb][r]);
        mx = fmaxf(mx, __shfl_xor(mx, 32));

        // ---- defer-max rescale (THR = 8*log2e) ----
        bool need = mx > m_run + 11.541560f;
        if (__any((int)need)) {
            float mn = fmaxf(m_run, mx);
            float sc = exp2_fast(m_run - mn);
            m_run = mn;
            acc_l *= sc;
#pragma unroll
            for (int d = 0; d < 2; d++)
#pragma unroll
                for (int r = 0; r < 16; r++) acc_o[d][r] *= sc;
        }

        // ---- P = exp2(S - m) in place; l partial sum ----
        float rs = 0.f;
#pragma unroll
        for (int kb = 0; kb < 2; kb++)
#pragma unroll
            for (int r = 0; r < 16; r++) {
                float p = exp2_fast(sacc[kb][r] - m_run);
                sacc[kb][r] = p;
                rs += p;
            }
        rs += __shfl_xor(rs, 32);
        acc_l += rs;

        // ---- PV: P B-frags via cvt_pk + cross-half shfl + select ----
#pragma unroll
        for (int ks = 0; ks < 4; ks++) {
            int kb = ks >> 1, u = ks & 1;
            unsigned int W0 = cvtpk(sacc[kb][8 * u + 0], sacc[kb][8 * u + 1]);
            unsigned int W1 = cvtpk(sacc[kb][8 * u + 2], sacc[kb][8 * u + 3]);
            unsigned int W2 = cvtpk(sacc[kb][8 * u + 4], sacc[kb][8 * u + 5]);
            unsigned int W3 = cvtpk(sacc[kb][8 * u + 6], sacc[kb][8 * u + 7]);
            unsigned int X0 = (unsigned int)__shfl_xor((int)W0, 32);
            unsigned int X1 = (unsigned int)__shfl_xor((int)W1, 32);
            unsigned int X2 = (unsigned int)__shfl_xor((int)W2, 32);
            unsigned int X3 = (unsigned int)__shfl_xor((int)W3, 32);
            u32x4 pw;
            pw[0] = lh ? X2 : W0;
            pw[1] = lh ? X3 : W1;
            pw[2] = lh ? W2 : X0;
            pw[3] = lh ? W3 : X1;
            us8 pf = __builtin_bit_cast(us8, pw);
#pragma unroll
            for (int dblk = 0; dblk < 2; dblk++) {
                int row = dblk * 32 + l31;
                int by = (row * 128 + (ks * 16 + 8 * lh) * 2) ^ ((row & 7) << 4);
                us8 vf = *(const us8*)(cV + by);
                acc_o[dblk] = mfma32(vf, pf, acc_o[dblk]);
            }
        }

        __syncthreads();   // drains stage(kvt+1); protects buf reuse
    }

    // ---- normalize + write [B*S][D] bf16 (d = dblk*32 + 8g + 4lh + 0..3) ----
    float inv = 1.f / acc_l;
    ushort_t* Orow = O + ((size_t)(b * SEQ) + q) * D_MODEL + h * DH;
#pragma unroll
    for (int dblk = 0; dblk < 2; dblk++)
#pragma unroll
        for (int g = 0; g < 4; g++) {
            unsigned int lo = cvtpk(acc_o[dblk][4 * g + 0] * inv,
                                    acc_o[dblk][4 * g + 1] * inv);
            unsigned int hi = cvtpk(acc_o[dblk][4 * g + 2] * inv,
                                    acc_o[dblk][4 * g + 3] * inv);
            uint2 pr; pr.x = lo; pr.y = hi;
            *(uint2*)(Orow + dblk * 32 + 8 * g + 4 * lh) = pr;
        }
#undef STAGE
}

// ---------------------------------------------------------------------------
extern "C" void kernel_launch(void* const* d_in, const int* in_sizes, int n_in,
                              void* d_out, int out_size, void* d_ws, size_t ws_size,
                              hipStream_t stream)
{
    const float* qx   = (const float*)d_in[0];
    const float* kx   = (const float*)d_in[1];
    const float* vx   = (const float*)d_in[2];
    const float* mask = (const float*)d_in[3];
    const float* wq   = (const float*)d_in[4];
    const float* wk   = (const float*)d_in[5];
    const float* wv   = (const float*)d_in[6];
    const float* w0   = (const float*)d_in[7];
    float* out = (float*)d_out;

    char* ws = (char*)d_ws;
    const size_t MB = 1024 * 1024;
    ushort_t* A0 = (ushort_t*)(ws);                 // 8 MB (qx bf16, then vx bf16)
    ushort_t* A1 = (ushort_t*)(ws + 8 * MB);        // 8 MB (kx bf16, then AO)
    ushort_t* Wq = (ushort_t*)(ws + 16 * MB);       // 2 MB each
    ushort_t* Wk = (ushort_t*)(ws + 18 * MB);
    ushort_t* Wv = (ushort_t*)(ws + 20 * MB);
    ushort_t* W0 = (ushort_t*)(ws + 22 * MB);
    ushort_t* VT = (ushort_t*)(ws + 24 * MB);       // [B,H,Dh,S] bf16, 8 MB
    int* flags   = (int*)(ws + 32 * MB);            // [32][32]
    ushort_t* AO = A1;                              // attn out reuses A1
    // Q and K (bf16, [B,H,S,Dh]) live in d_out until attn consumes them
    ushort_t* Qb = (ushort_t*)d_out;
    ushort_t* Kb = (ushort_t*)d_out + 4 * MB;       // +8 MB bytes

    hipMemsetAsync(flags, 0, 32 * 32 * sizeof(int), stream);
    mask_flags<<<dim3(32, 32), 256, 0, stream>>>(mask, flags);

    // weights fp32 -> bf16 (one fused launch)
    conv_multi<<<dim3(256, 1, 4), 256, 0, stream>>>(wq, Wq, wk, Wk, wv, Wv, w0, W0, 262144);
    // qx, kx fp32 -> bf16
    conv_multi<<<dim3(1024, 1, 2), 256, 0, stream>>>(qx, A0, kx, A1, qx, A0, qx, A0, 1048576);

    gemm_qk<<<dim3(32, 16, 2), 256, 0, stream>>>(A0, A1, Wq, Wk, Qb, Kb);

    // vx fp32 -> bf16 (A0 free after gemm_qk)
    conv_multi<<<dim3(1024, 1, 1), 256, 0, stream>>>(vx, A0, vx, A0, vx, A0, vx, A0, 1048576);
    gemm_v<<<dim3(32, 16), 256, 0, stream>>>(A0, Wv, VT);

    attn_fwd<<<512, 256, 0, stream>>>(Qb, Kb, VT, mask, flags, AO);

    gemm_o<<<dim3(32, 16), 256, 0, stream>>>(AO, W0, out);
}

// Round 9
// 153.346 us; speedup vs baseline: 2.4881x; 1.0210x over previous
//
#include <hip/hip_runtime.h>
#include <hip/hip_bf16.h>
#include <stdint.h>

#define D_MODEL 1024
#define NH 16
#define DH 64
#define SEQ 2048
#define MROWS 4096   // B*S
#define LOG2E 1.44269504088896340736f

typedef unsigned short ushort_t;
typedef __attribute__((ext_vector_type(4))) float f32x4;
typedef __attribute__((ext_vector_type(16))) float f32x16;
typedef __attribute__((ext_vector_type(4))) unsigned short us4;
typedef __attribute__((ext_vector_type(8))) unsigned short us8;
typedef __attribute__((ext_vector_type(4))) unsigned int u32x4;
typedef __attribute__((ext_vector_type(8))) __bf16 bf16x8;

__device__ __forceinline__ f32x4 mfma16(us8 a, us8 b, f32x4 c) {
    return __builtin_amdgcn_mfma_f32_16x16x32_bf16(
        __builtin_bit_cast(bf16x8, a), __builtin_bit_cast(bf16x8, b), c, 0, 0, 0);
}
__device__ __forceinline__ f32x16 mfma32(us8 a, us8 b, f32x16 c) {
    return __builtin_amdgcn_mfma_f32_32x32x16_bf16(
        __builtin_bit_cast(bf16x8, a), __builtin_bit_cast(bf16x8, b), c, 0, 0, 0);
}

// fp32 -> bf16 round-to-nearest-even (finite inputs)
__device__ __forceinline__ ushort_t f2bf(float f) {
    union { float f; uint32_t u; } v; v.f = f;
    uint32_t r = v.u + 0x7fffu + ((v.u >> 16) & 1u);
    return (ushort_t)(r >> 16);
}

// packed f32x2 -> bf16x2 (documented: src0 -> low half)
__device__ __forceinline__ unsigned int cvtpk(float lo, float hi) {
    unsigned int r;
    asm("v_cvt_pk_bf16_f32 %0, %1, %2" : "=v"(r) : "v"(lo), "v"(hi));
    return r;
}

__device__ __forceinline__ float exp2_fast(float x) {
#if __has_builtin(__builtin_amdgcn_exp2f)
    return __builtin_amdgcn_exp2f(x);
#else
    float r; asm("v_exp_f32 %0, %1" : "=v"(r) : "v"(x)); return r;
#endif
}

// async global->LDS, 16B per lane; LDS base wave-uniform, lane i at base+i*16
__device__ __forceinline__ void gload16(const void* g, void* l) {
    __builtin_amdgcn_global_load_lds(
        (const __attribute__((address_space(1))) void*)g,
        (__attribute__((address_space(3))) void*)l, 16, 0, 0);
}

// ---------------------------------------------------------------------------
// fused fp32 -> bf16 convert; blockIdx.z picks (src,dst) pair; n4 = float4 count
// ---------------------------------------------------------------------------
__global__ __launch_bounds__(256) void conv_multi(
    const float* __restrict__ s0, ushort_t* __restrict__ d0,
    const float* __restrict__ s1, ushort_t* __restrict__ d1,
    const float* __restrict__ s2, ushort_t* __restrict__ d2,
    const float* __restrict__ s3, ushort_t* __restrict__ d3, int n4)
{
    int z = blockIdx.z;
    const float* s = z == 0 ? s0 : z == 1 ? s1 : z == 2 ? s2 : s3;
    ushort_t* d    = z == 0 ? d0 : z == 1 ? d1 : z == 2 ? d2 : d3;
    int i = blockIdx.x * 256 + threadIdx.x;
    int stride = gridDim.x * 256;
    for (; i < n4; i += stride) {
        float4 v = ((const float4*)s)[i];
        us4 o;
        o[0] = f2bf(v.x); o[1] = f2bf(v.y); o[2] = f2bf(v.z); o[3] = f2bf(v.w);
        ((us4*)d)[i] = o;
    }
}

// ---------------------------------------------------------------------------
// mask tile flags at 64x64 granularity
// ---------------------------------------------------------------------------
__global__ __launch_bounds__(256) void mask_flags(const float* __restrict__ mask,
                                                  int* __restrict__ flags)
{
    int qt = blockIdx.x, kt = blockIdx.y;
    int t = threadIdx.x;
    bool nz = false;
#pragma unroll
    for (int i = 0; i < 4; i++) {
        int idx = t + i * 256;               // 1024 float4: 64 rows x 16
        int row = idx >> 4, c4 = (idx & 15) * 4;
        float4 v = *(const float4*)(mask + (size_t)(qt * 64 + row) * SEQ + kt * 64 + c4);
        nz |= (v.x != 0.f) | (v.y != 0.f) | (v.z != 0.f) | (v.w != 0.f);
    }
    if (__any((int)nz) && (t & 63) == 0) atomicOr(&flags[qt * 32 + kt], 1);
}

// ---------------------------------------------------------------------------
// shared GEMM core, DOUBLE-BUFFERED 2-phase: per K-step {ds_read frags ->
// issue stage(next) -> MFMA -> barrier}. Stage issued AFTER the reads so the
// compiler's conservative LDS-alias vmcnt wait can't serialize the pipeline.
// Race-free: buffer cur^1 staged at step t was last read at step t-1, and
// those reads completed before t-1's MFMA (lgkmcnt), which precedes the
// barrier. C = A[4096][1024] @ W^T, BM=128 BN=64 BK=64, gload16 staging.
// ---------------------------------------------------------------------------
__device__ __forceinline__ void gemm_stage(const ushort_t* __restrict__ A,
                                           const ushort_t* __restrict__ B,
                                           int m0, int n0, int t, int w, int k0,
                                           ushort_t* sA, ushort_t* sB)
{
#pragma unroll
    for (int r = 0; r < 4; r++) {
        int chunk = r * 256 + t;                   // 1024 chunks of 8 bf16
        int row = chunk >> 3, c8 = (chunk & 7) * 8;
        gload16(A + (size_t)(m0 + row) * D_MODEL + k0 + c8,
                &sA[(r * 256 + w * 64) * 8]);
    }
#pragma unroll
    for (int r = 0; r < 2; r++) {
        int chunk = r * 256 + t;
        int row = chunk >> 3, c8 = (chunk & 7) * 8;
        gload16(B + (size_t)(n0 + row) * D_MODEL + k0 + c8,
                &sB[(r * 256 + w * 64) * 8]);
    }
}

__device__ __forceinline__ void gemm_core(const ushort_t* __restrict__ A,
                                          const ushort_t* __restrict__ B,
                                          int m0, int n0, int t,
                                          ushort_t* sA, ushort_t* sB,  // [2][..]
                                          f32x4 acc[4][2])
{
    const int lane = t & 63, w = t >> 6;
    const int lr = lane & 15, lg = lane >> 4;
    const int wm = (w >> 1) * 64, wn = (w & 1) * 32;

    gemm_stage(A, B, m0, n0, t, w, 0, sA, sB);
    __syncthreads();

    for (int it = 0; it < D_MODEL / 64; ++it) {
        const int cur = it & 1;
        const ushort_t* cA = sA + cur * (128 * 64);
        const ushort_t* cB = sB + cur * (64 * 64);

        // ---- ds_read all fragments of current buffer FIRST ----
        us8 af[4][2], bfr[2][2];
#pragma unroll
        for (int i = 0; i < 4; i++)
#pragma unroll
            for (int ks = 0; ks < 2; ks++)
                af[i][ks] = *(const us8*)&cA[(wm + i * 16 + lr) * 64 + ks * 32 + 8 * lg];
#pragma unroll
        for (int j = 0; j < 2; j++)
#pragma unroll
            for (int ks = 0; ks < 2; ks++)
                bfr[j][ks] = *(const us8*)&cB[(wn + j * 16 + lr) * 64 + ks * 32 + 8 * lg];

        // ---- now issue next-tile stage (no later ds_read to stall on) ----
        if (it + 1 < D_MODEL / 64)
            gemm_stage(A, B, m0, n0, t, w, (it + 1) * 64,
                       sA + (cur ^ 1) * (128 * 64), sB + (cur ^ 1) * (64 * 64));

        // ---- MFMA (waits lgkm for frags only; loads fly underneath) ----
#pragma unroll
        for (int i = 0; i < 4; i++)
#pragma unroll
            for (int j = 0; j < 2; j++)
#pragma unroll
                for (int ks = 0; ks < 2; ks++)
                    acc[i][j] = mfma16(af[i][ks], bfr[j][ks], acc[i][j]);

        __syncthreads();   // drains stage; protects buffer switch
    }
}

// Q/K projections (z=0: Q scaled by 0.125*log2e, z=1: K). C layout [B,H,S,Dh] bf16.
__global__ __launch_bounds__(256) void gemm_qk(const ushort_t* __restrict__ A0,
                                               const ushort_t* __restrict__ A1,
                                               const ushort_t* __restrict__ Wq,
                                               const ushort_t* __restrict__ Wk,
                                               ushort_t* __restrict__ Qo,
                                               ushort_t* __restrict__ Ko)
{
    __shared__ ushort_t sA[2][128 * 64];
    __shared__ ushort_t sB[2][64 * 64];
    const int z = blockIdx.z;
    const ushort_t* A = z ? A1 : A0;
    const ushort_t* W = z ? Wk : Wq;
    ushort_t* C = z ? Ko : Qo;
    const float scale = z ? 1.0f : 0.125f * LOG2E;   // scores in log2 units
    const int t = threadIdx.x, lane = t & 63, w = t >> 6;
    const int lr = lane & 15, lg = lane >> 4;
    const int wm = (w >> 1) * 64, wn = (w & 1) * 32;
    const int m0 = blockIdx.x * 128, n0 = blockIdx.y * 64;

    f32x4 acc[4][2];
    f32x4 zero = {0.f, 0.f, 0.f, 0.f};
#pragma unroll
    for (int i = 0; i < 4; i++)
#pragma unroll
        for (int j = 0; j < 2; j++) acc[i][j] = zero;
    gemm_core(A, W, m0, n0, t, &sA[0][0], &sB[0][0], acc);

#pragma unroll
    for (int i = 0; i < 4; i++)
#pragma unroll
        for (int j = 0; j < 2; j++)
#pragma unroll
            for (int r = 0; r < 4; r++) {
                int m = m0 + wm + i * 16 + 4 * lg + r;   // token (b*S+s)
                int n = n0 + wn + j * 16 + lr;           // feature
                int b = m >> 11, s = m & 2047;
                int h = n >> 6, dh = n & 63;
                C[(((size_t)(b * NH + h)) * SEQ + s) * DH + dh] = f2bf(acc[i][j][r] * scale);
            }
}

// V projection -> transposed output VT [B,H,Dh,S] bf16 (r-packed us4 stores)
__global__ __launch_bounds__(256) void gemm_v(const ushort_t* __restrict__ A,
                                              const ushort_t* __restrict__ W,
                                              ushort_t* __restrict__ VT)
{
    __shared__ ushort_t sA[2][128 * 64];
    __shared__ ushort_t sB[2][64 * 64];
    const int t = threadIdx.x, lane = t & 63, w = t >> 6;
    const int lr = lane & 15, lg = lane >> 4;
    const int wm = (w >> 1) * 64, wn = (w & 1) * 32;
    const int m0 = blockIdx.x * 128, n0 = blockIdx.y * 64;

    f32x4 acc[4][2];
    f32x4 zero = {0.f, 0.f, 0.f, 0.f};
#pragma unroll
    for (int i = 0; i < 4; i++)
#pragma unroll
        for (int j = 0; j < 2; j++) acc[i][j] = zero;
    gemm_core(A, W, m0, n0, t, &sA[0][0], &sB[0][0], acc);

#pragma unroll
    for (int i = 0; i < 4; i++)
#pragma unroll
        for (int j = 0; j < 2; j++) {
            int m = m0 + wm + i * 16 + 4 * lg;           // s base; r adds 0..3
            int n = n0 + wn + j * 16 + lr;
            int b = m >> 11, s = m & 2047;
            int h = n >> 6, dh = n & 63;
            us4 o;
#pragma unroll
            for (int r = 0; r < 4; r++) o[r] = f2bf(acc[i][j][r]);
            *(us4*)&VT[(((size_t)(b * NH + h)) * DH + dh) * SEQ + s] = o;
        }
}

// output projection: A bf16 [4096][1024] @ W0^T -> fp32 [4096][1024]
__global__ __launch_bounds__(256) void gemm_o(const ushort_t* __restrict__ A,
                                              const ushort_t* __restrict__ W,
                                              float* __restrict__ C)
{
    __shared__ ushort_t sA[2][128 * 64];
    __shared__ ushort_t sB[2][64 * 64];
    const int t = threadIdx.x, lane = t & 63, w = t >> 6;
    const int lr = lane & 15, lg = lane >> 4;
    const int wm = (w >> 1) * 64, wn = (w & 1) * 32;
    const int m0 = blockIdx.x * 128, n0 = blockIdx.y * 64;

    f32x4 acc[4][2];
    f32x4 zero = {0.f, 0.f, 0.f, 0.f};
#pragma unroll
    for (int i = 0; i < 4; i++)
#pragma unroll
        for (int j = 0; j < 2; j++) acc[i][j] = zero;
    gemm_core(A, W, m0, n0, t, &sA[0][0], &sB[0][0], acc);

#pragma unroll
    for (int i = 0; i < 4; i++)
#pragma unroll
        for (int j = 0; j < 2; j++)
#pragma unroll
            for (int r = 0; r < 4; r++) {
                int m = m0 + wm + i * 16 + 4 * lg + r;
                int n = n0 + wn + j * 16 + lr;
                C[(size_t)m * D_MODEL + n] = acc[i][j][r];
            }
}

// ---------------------------------------------------------------------------
// Flash attention, swapped-operand 32x32x16 form:
//   S = mfma32(K, Q) -> S[kcol][q], q = lane&31  => per-lane scalar softmax
//   P in registers: cvt_pk pairs + __shfl_xor(32) + select assemble PV B-frags
//   (VERIFIED in round 7; permlane32_swap direction failed twice — abandoned)
//   O = mfma32(V, P) -> O[d][q]
// Pipeline order per tile: K-reads+QK -> V-reads -> STAGE(next) -> softmax
// -> PV -> barrier.  Stage issued after ALL ds_reads of the tile so the
// compiler's LDS-alias vmcnt wait can't serialize; loads hide under softmax.
// C/D layout (HW-verified): col=lane&31, row=(r&3)+8*(r>>2)+4*(lane>>5).
// ---------------------------------------------------------------------------
__global__ __launch_bounds__(256, 2) void attn_fwd(const ushort_t* __restrict__ Q,
                                                   const ushort_t* __restrict__ K,
                                                   const ushort_t* __restrict__ VT,
                                                   const float* __restrict__ mask,
                                                   const int* __restrict__ flags,
                                                   ushort_t* __restrict__ O)
{
    __shared__ ushort_t sK[2][64 * 64];
    __shared__ ushort_t sVT[2][64 * 64];    // rows = d, cols = kv

    const int t = threadIdx.x, lane = t & 63, w = t >> 6;
    const int l31 = lane & 31, lh = lane >> 5;
    const int id = blockIdx.x;
    const int bh = (id & 7) * 4 + ((id >> 3) >> 4);   // XCD-contiguous heads
    const int qt = (id >> 3) & 15;
    const int b = bh >> 4, h = bh & 15;
    const int q = qt * 128 + w * 32 + l31;   // lane's q row

    // mask-tile flags for this 128-row q block (2 flag rows ORed)
    unsigned long long blt = __ballot(flags[(qt * 2 + lh) * 32 + l31] != 0);
    const unsigned int fl = (unsigned int)(blt | (blt >> 32));

    // Q fragments: B-operand rows = q, k(d)-slots 16*ks + 8*lh + e
    us8 qfr[4];
#pragma unroll
    for (int ks = 0; ks < 4; ks++)
        qfr[ks] = *(const us8*)(Q + ((size_t)bh * SEQ + q) * DH + ks * 16 + 8 * lh);

    f32x16 acc_o[2];
#pragma unroll
    for (int d = 0; d < 2; d++)
#pragma unroll
        for (int r = 0; r < 16; r++) acc_o[d][r] = 0.f;
    float acc_l = 0.f, m_run = -1e30f;

    const ushort_t* Kb = K + (size_t)bh * SEQ * DH;
    const ushort_t* Vb = VT + (size_t)bh * DH * SEQ;

    // staging: 256 threads x 2 chunks per tensor per tile
#define STAGE(kvt_, buf_)                                                     \
    {                                                                         \
        _Pragma("unroll")                                                     \
        for (int r = 0; r < 2; r++) {                                         \
            int j = r * 256 + t;                                              \
            int row = j >> 3, cc = (j & 7) ^ (row & 7);                       \
            gload16(Kb + (size_t)((kvt_) * 64 + row) * DH + cc * 8,           \
                    &sK[buf_][(r * 256 + w * 64) * 8]);                       \
        }                                                                     \
        _Pragma("unroll")                                                     \
        for (int r = 0; r < 2; r++) {                                         \
            int j = r * 256 + t;                                              \
            int row = j >> 3, cc = (j & 7) ^ (row & 7);                       \
            gload16(Vb + (size_t)row * SEQ + (kvt_) * 64 + cc * 8,            \
                    &sVT[buf_][(r * 256 + w * 64) * 8]);                      \
        }                                                                     \
    }

    STAGE(0, 0);
    __syncthreads();

    for (int kvt = 0; kvt < SEQ / 64; ++kvt) {
        const int cur = kvt & 1;
        const char* cK = (const char*)sK[cur];
        const char* cV = (const char*)sVT[cur];

        // ---- S = K Q^T: sacc[kb][r] = S[kcol=kb*32+crow(r,lh)][q] ----
        f32x16 sacc[2];
#pragma unroll
        for (int kb = 0; kb < 2; kb++)
#pragma unroll
            for (int r = 0; r < 16; r++) sacc[kb][r] = 0.f;
#pragma unroll
        for (int ks = 0; ks < 4; ks++)
#pragma unroll
            for (int kb = 0; kb < 2; kb++) {
                int row = kb * 32 + l31;
                int by = (row * 128 + (ks * 16 + 8 * lh) * 2) ^ ((row & 7) << 4);
                us8 kf = *(const us8*)(cK + by);
                sacc[kb] = mfma32(kf, qfr[ks], sacc[kb]);
            }

        // ---- V-frag reads, all upfront (last ds_reads of this tile) ----
        us8 vf[4][2];
#pragma unroll
        for (int ks = 0; ks < 4; ks++)
#pragma unroll
            for (int dblk = 0; dblk < 2; dblk++) {
                int row = dblk * 32 + l31;
                int by = (row * 128 + (ks * 16 + 8 * lh) * 2) ^ ((row & 7) << 4);
                vf[ks][dblk] = *(const us8*)(cV + by);
            }

        // ---- stage next tile; loads hide under softmax + PV ----
        if (kvt + 1 < SEQ / 64) STAGE(kvt + 1, cur ^ 1);

        // ---- additive mask (log2; skipped when tile all-zero) ----
        if ((fl >> kvt) & 1u) {
#pragma unroll
            for (int kb = 0; kb < 2; kb++)
#pragma unroll
                for (int r = 0; r < 16; r++) {
                    int kcol = kb * 32 + (r & 3) + 8 * (r >> 2) + 4 * lh;
                    sacc[kb][r] += mask[(size_t)q * SEQ + kvt * 64 + kcol] * LOG2E;
                }
        }

        // ---- row max: in-lane tree + 1 cross-half shfl ----
        float mx = sacc[0][0];
#pragma unroll
        for (int kb = 0; kb < 2; kb++)
#pragma unroll
            for (int r = 0; r < 16; r++) mx = fmaxf(mx, sacc[kb][r]);
        mx = fmaxf(mx, __shfl_xor(mx, 32));

        // ---- defer-max rescale (THR = 8*log2e) ----
        bool need = mx > m_run + 11.541560f;
        if (__any((int)need)) {
            float mn = fmaxf(m_run, mx);
            float sc = exp2_fast(m_run - mn);
            m_run = mn;
            acc_l *= sc;
#pragma unroll
            for (int d = 0; d < 2; d++)
#pragma unroll
                for (int r = 0; r < 16; r++) acc_o[d][r] *= sc;
        }

        // ---- P = exp2(S - m) in place; l partial sum ----
        float rs = 0.f;
#pragma unroll
        for (int kb = 0; kb < 2; kb++)
#pragma unroll
            for (int r = 0; r < 16; r++) {
                float p = exp2_fast(sacc[kb][r] - m_run);
                sacc[kb][r] = p;
                rs += p;
            }
        rs += __shfl_xor(rs, 32);
        acc_l += rs;

        // ---- PV: P B-frags via cvt_pk + cross-half shfl + select (verified) ----
#pragma unroll
        for (int ks = 0; ks < 4; ks++) {
            int kb = ks >> 1, u = ks & 1;
            unsigned int W0 = cvtpk(sacc[kb][8 * u + 0], sacc[kb][8 * u + 1]);
            unsigned int W1 = cvtpk(sacc[kb][8 * u + 2], sacc[kb][8 * u + 3]);
            unsigned int W2 = cvtpk(sacc[kb][8 * u + 4], sacc[kb][8 * u + 5]);
            unsigned int W3 = cvtpk(sacc[kb][8 * u + 6], sacc[kb][8 * u + 7]);
            unsigned int X0 = (unsigned int)__shfl_xor((int)W0, 32);
            unsigned int X1 = (unsigned int)__shfl_xor((int)W1, 32);
            unsigned int X2 = (unsigned int)__shfl_xor((int)W2, 32);
            unsigned int X3 = (unsigned int)__shfl_xor((int)W3, 32);
            u32x4 pw;
            pw[0] = lh ? X2 : W0;
            pw[1] = lh ? X3 : W1;
            pw[2] = lh ? W2 : X0;
            pw[3] = lh ? W3 : X1;
            us8 pf = __builtin_bit_cast(us8, pw);
#pragma unroll
            for (int dblk = 0; dblk < 2; dblk++)
                acc_o[dblk] = mfma32(vf[ks][dblk], pf, acc_o[dblk]);
        }

        __syncthreads();   // drains stage(kvt+1); protects buf reuse
    }

    // ---- normalize + write [B*S][D] bf16 (d = dblk*32 + 8g + 4lh + 0..3) ----
    float inv = 1.f / acc_l;
    ushort_t* Orow = O + ((size_t)(b * SEQ) + q) * D_MODEL + h * DH;
#pragma unroll
    for (int dblk = 0; dblk < 2; dblk++)
#pragma unroll
        for (int g = 0; g < 4; g++) {
            unsigned int lo = cvtpk(acc_o[dblk][4 * g + 0] * inv,
                                    acc_o[dblk][4 * g + 1] * inv);
            unsigned int hi = cvtpk(acc_o[dblk][4 * g + 2] * inv,
                                    acc_o[dblk][4 * g + 3] * inv);
            uint2 pr; pr.x = lo; pr.y = hi;
            *(uint2*)(Orow + dblk * 32 + 8 * g + 4 * lh) = pr;
        }
#undef STAGE
}

// ---------------------------------------------------------------------------
extern "C" void kernel_launch(void* const* d_in, const int* in_sizes, int n_in,
                              void* d_out, int out_size, void* d_ws, size_t ws_size,
                              hipStream_t stream)
{
    const float* qx   = (const float*)d_in[0];
    const float* kx   = (const float*)d_in[1];
    const float* vx   = (const float*)d_in[2];
    const float* mask = (const float*)d_in[3];
    const float* wq   = (const float*)d_in[4];
    const float* wk   = (const float*)d_in[5];
    const float* wv   = (const float*)d_in[6];
    const float* w0   = (const float*)d_in[7];
    float* out = (float*)d_out;

    char* ws = (char*)d_ws;
    const size_t MB = 1024 * 1024;
    ushort_t* A0 = (ushort_t*)(ws);                 // 8 MB (qx bf16, then vx bf16)
    ushort_t* A1 = (ushort_t*)(ws + 8 * MB);        // 8 MB (kx bf16, then AO)
    ushort_t* Wq = (ushort_t*)(ws + 16 * MB);       // 2 MB each
    ushort_t* Wk = (ushort_t*)(ws + 18 * MB);
    ushort_t* Wv = (ushort_t*)(ws + 20 * MB);
    ushort_t* W0 = (ushort_t*)(ws + 22 * MB);
    ushort_t* VT = (ushort_t*)(ws + 24 * MB);       // [B,H,Dh,S] bf16, 8 MB
    int* flags   = (int*)(ws + 32 * MB);            // [32][32]
    ushort_t* AO = A1;                              // attn out reuses A1
    // Q and K (bf16, [B,H,S,Dh]) live in d_out until attn consumes them
    ushort_t* Qb = (ushort_t*)d_out;
    ushort_t* Kb = (ushort_t*)d_out + 4 * MB;       // +8 MB bytes

    hipMemsetAsync(flags, 0, 32 * 32 * sizeof(int), stream);
    mask_flags<<<dim3(32, 32), 256, 0, stream>>>(mask, flags);

    // weights fp32 -> bf16 (one fused launch)
    conv_multi<<<dim3(256, 1, 4), 256, 0, stream>>>(wq, Wq, wk, Wk, wv, Wv, w0, W0, 262144);
    // qx, kx fp32 -> bf16
    conv_multi<<<dim3(1024, 1, 2), 256, 0, stream>>>(qx, A0, kx, A1, qx, A0, qx, A0, 1048576);

    gemm_qk<<<dim3(32, 16, 2), 256, 0, stream>>>(A0, A1, Wq, Wk, Qb, Kb);

    // vx fp32 -> bf16 (A0 free after gemm_qk)
    conv_multi<<<dim3(1024, 1, 1), 256, 0, stream>>>(vx, A0, vx, A0, vx, A0, vx, A0, 1048576);
    gemm_v<<<dim3(32, 16), 256, 0, stream>>>(A0, Wv, VT);

    attn_fwd<<<512, 256, 0, stream>>>(Qb, Kb, VT, mask, flags, AO);

    gemm_o<<<dim3(32, 16), 256, 0, stream>>>(AO, W0, out);
}

// Round 10
// 149.391 us; speedup vs baseline: 2.5540x; 1.0265x over previous
//
#include <hip/hip_runtime.h>
#include <hip/hip_bf16.h>
#include <stdint.h>

#define D_MODEL 1024
#define NH 16
#define DH 64
#define SEQ 2048
#define MROWS 4096   // B*S
#define LOG2E 1.44269504088896340736f

typedef unsigned short ushort_t;
typedef __attribute__((ext_vector_type(4))) float f32x4;
typedef __attribute__((ext_vector_type(16))) float f32x16;
typedef __attribute__((ext_vector_type(4))) unsigned short us4;
typedef __attribute__((ext_vector_type(8))) unsigned short us8;
typedef __attribute__((ext_vector_type(4))) unsigned int u32x4;
typedef __attribute__((ext_vector_type(8))) __bf16 bf16x8;

__device__ __forceinline__ f32x4 mfma16(us8 a, us8 b, f32x4 c) {
    return __builtin_amdgcn_mfma_f32_16x16x32_bf16(
        __builtin_bit_cast(bf16x8, a), __builtin_bit_cast(bf16x8, b), c, 0, 0, 0);
}
__device__ __forceinline__ f32x16 mfma32(us8 a, us8 b, f32x16 c) {
    return __builtin_amdgcn_mfma_f32_32x32x16_bf16(
        __builtin_bit_cast(bf16x8, a), __builtin_bit_cast(bf16x8, b), c, 0, 0, 0);
}

// fp32 -> bf16 round-to-nearest-even (finite inputs)
__device__ __forceinline__ ushort_t f2bf(float f) {
    union { float f; uint32_t u; } v; v.f = f;
    uint32_t r = v.u + 0x7fffu + ((v.u >> 16) & 1u);
    return (ushort_t)(r >> 16);
}

// packed f32x2 -> bf16x2 (documented: src0 -> low half)
__device__ __forceinline__ unsigned int cvtpk(float lo, float hi) {
    unsigned int r;
    asm("v_cvt_pk_bf16_f32 %0, %1, %2" : "=v"(r) : "v"(lo), "v"(hi));
    return r;
}

__device__ __forceinline__ float exp2_fast(float x) {
#if __has_builtin(__builtin_amdgcn_exp2f)
    return __builtin_amdgcn_exp2f(x);
#else
    float r; asm("v_exp_f32 %0, %1" : "=v"(r) : "v"(x)); return r;
#endif
}

// async global->LDS, 16B per lane; LDS base wave-uniform, lane i at base+i*16
__device__ __forceinline__ void gload16(const void* g, void* l) {
    __builtin_amdgcn_global_load_lds(
        (const __attribute__((address_space(1))) void*)g,
        (__attribute__((address_space(3))) void*)l, 16, 0, 0);
}

// ---------------------------------------------------------------------------
// fused fp32 -> bf16 convert; blockIdx.z picks (src,dst) pair; n4 = float4 count
// ---------------------------------------------------------------------------
__global__ __launch_bounds__(256) void conv_multi(
    const float* __restrict__ s0, ushort_t* __restrict__ d0,
    const float* __restrict__ s1, ushort_t* __restrict__ d1,
    const float* __restrict__ s2, ushort_t* __restrict__ d2,
    const float* __restrict__ s3, ushort_t* __restrict__ d3, int n4)
{
    int z = blockIdx.z;
    const float* s = z == 0 ? s0 : z == 1 ? s1 : z == 2 ? s2 : s3;
    ushort_t* d    = z == 0 ? d0 : z == 1 ? d1 : z == 2 ? d2 : d3;
    int i = blockIdx.x * 256 + threadIdx.x;
    int stride = gridDim.x * 256;
    for (; i < n4; i += stride) {
        float4 v = ((const float4*)s)[i];
        us4 o;
        o[0] = f2bf(v.x); o[1] = f2bf(v.y); o[2] = f2bf(v.z); o[3] = f2bf(v.w);
        ((us4*)d)[i] = o;
    }
}

// ---------------------------------------------------------------------------
// mask tile flags at 64x64 granularity
// ---------------------------------------------------------------------------
__global__ __launch_bounds__(256) void mask_flags(const float* __restrict__ mask,
                                                  int* __restrict__ flags)
{
    int qt = blockIdx.x, kt = blockIdx.y;
    int t = threadIdx.x;
    bool nz = false;
#pragma unroll
    for (int i = 0; i < 4; i++) {
        int idx = t + i * 256;               // 1024 float4: 64 rows x 16
        int row = idx >> 4, c4 = (idx & 15) * 4;
        float4 v = *(const float4*)(mask + (size_t)(qt * 64 + row) * SEQ + kt * 64 + c4);
        nz |= (v.x != 0.f) | (v.y != 0.f) | (v.z != 0.f) | (v.w != 0.f);
    }
    if (__any((int)nz) && (t & 63) == 0) atomicOr(&flags[qt * 32 + kt], 1);
}

// ---------------------------------------------------------------------------
// shared GEMM core, DOUBLE-BUFFERED 2-phase (verified round 9)
// ---------------------------------------------------------------------------
__device__ __forceinline__ void gemm_stage(const ushort_t* __restrict__ A,
                                           const ushort_t* __restrict__ B,
                                           int m0, int n0, int t, int w, int k0,
                                           ushort_t* sA, ushort_t* sB)
{
#pragma unroll
    for (int r = 0; r < 4; r++) {
        int chunk = r * 256 + t;                   // 1024 chunks of 8 bf16
        int row = chunk >> 3, c8 = (chunk & 7) * 8;
        gload16(A + (size_t)(m0 + row) * D_MODEL + k0 + c8,
                &sA[(r * 256 + w * 64) * 8]);
    }
#pragma unroll
    for (int r = 0; r < 2; r++) {
        int chunk = r * 256 + t;
        int row = chunk >> 3, c8 = (chunk & 7) * 8;
        gload16(B + (size_t)(n0 + row) * D_MODEL + k0 + c8,
                &sB[(r * 256 + w * 64) * 8]);
    }
}

__device__ __forceinline__ void gemm_core(const ushort_t* __restrict__ A,
                                          const ushort_t* __restrict__ B,
                                          int m0, int n0, int t,
                                          ushort_t* sA, ushort_t* sB,  // [2][..]
                                          f32x4 acc[4][2])
{
    const int lane = t & 63, w = t >> 6;
    const int lr = lane & 15, lg = lane >> 4;
    const int wm = (w >> 1) * 64, wn = (w & 1) * 32;

    gemm_stage(A, B, m0, n0, t, w, 0, sA, sB);
    __syncthreads();

    for (int it = 0; it < D_MODEL / 64; ++it) {
        const int cur = it & 1;
        const ushort_t* cA = sA + cur * (128 * 64);
        const ushort_t* cB = sB + cur * (64 * 64);

        us8 af[4][2], bfr[2][2];
#pragma unroll
        for (int i = 0; i < 4; i++)
#pragma unroll
            for (int ks = 0; ks < 2; ks++)
                af[i][ks] = *(const us8*)&cA[(wm + i * 16 + lr) * 64 + ks * 32 + 8 * lg];
#pragma unroll
        for (int j = 0; j < 2; j++)
#pragma unroll
            for (int ks = 0; ks < 2; ks++)
                bfr[j][ks] = *(const us8*)&cB[(wn + j * 16 + lr) * 64 + ks * 32 + 8 * lg];

        if (it + 1 < D_MODEL / 64)
            gemm_stage(A, B, m0, n0, t, w, (it + 1) * 64,
                       sA + (cur ^ 1) * (128 * 64), sB + (cur ^ 1) * (64 * 64));

#pragma unroll
        for (int i = 0; i < 4; i++)
#pragma unroll
            for (int j = 0; j < 2; j++)
#pragma unroll
                for (int ks = 0; ks < 2; ks++)
                    acc[i][j] = mfma16(af[i][ks], bfr[j][ks], acc[i][j]);

        __syncthreads();
    }
}

// Q/K projections (z=0: Q scaled by 0.125*log2e, z=1: K). C layout [B,H,S,Dh] bf16.
__global__ __launch_bounds__(256) void gemm_qk(const ushort_t* __restrict__ A0,
                                               const ushort_t* __restrict__ A1,
                                               const ushort_t* __restrict__ Wq,
                                               const ushort_t* __restrict__ Wk,
                                               ushort_t* __restrict__ Qo,
                                               ushort_t* __restrict__ Ko)
{
    __shared__ ushort_t sA[2][128 * 64];
    __shared__ ushort_t sB[2][64 * 64];
    const int z = blockIdx.z;
    const ushort_t* A = z ? A1 : A0;
    const ushort_t* W = z ? Wk : Wq;
    ushort_t* C = z ? Ko : Qo;
    const float scale = z ? 1.0f : 0.125f * LOG2E;   // scores in log2 units
    const int t = threadIdx.x, lane = t & 63, w = t >> 6;
    const int lr = lane & 15, lg = lane >> 4;
    const int wm = (w >> 1) * 64, wn = (w & 1) * 32;
    const int m0 = blockIdx.x * 128, n0 = blockIdx.y * 64;

    f32x4 acc[4][2];
    f32x4 zero = {0.f, 0.f, 0.f, 0.f};
#pragma unroll
    for (int i = 0; i < 4; i++)
#pragma unroll
        for (int j = 0; j < 2; j++) acc[i][j] = zero;
    gemm_core(A, W, m0, n0, t, &sA[0][0], &sB[0][0], acc);

#pragma unroll
    for (int i = 0; i < 4; i++)
#pragma unroll
        for (int j = 0; j < 2; j++)
#pragma unroll
            for (int r = 0; r < 4; r++) {
                int m = m0 + wm + i * 16 + 4 * lg + r;   // token (b*S+s)
                int n = n0 + wn + j * 16 + lr;           // feature
                int b = m >> 11, s = m & 2047;
                int h = n >> 6, dh = n & 63;
                C[(((size_t)(b * NH + h)) * SEQ + s) * DH + dh] = f2bf(acc[i][j][r] * scale);
            }
}

// V projection -> transposed output VT [B,H,Dh,S] bf16 (r-packed us4 stores)
__global__ __launch_bounds__(256) void gemm_v(const ushort_t* __restrict__ A,
                                              const ushort_t* __restrict__ W,
                                              ushort_t* __restrict__ VT)
{
    __shared__ ushort_t sA[2][128 * 64];
    __shared__ ushort_t sB[2][64 * 64];
    const int t = threadIdx.x, lane = t & 63, w = t >> 6;
    const int lr = lane & 15, lg = lane >> 4;
    const int wm = (w >> 1) * 64, wn = (w & 1) * 32;
    const int m0 = blockIdx.x * 128, n0 = blockIdx.y * 64;

    f32x4 acc[4][2];
    f32x4 zero = {0.f, 0.f, 0.f, 0.f};
#pragma unroll
    for (int i = 0; i < 4; i++)
#pragma unroll
        for (int j = 0; j < 2; j++) acc[i][j] = zero;
    gemm_core(A, W, m0, n0, t, &sA[0][0], &sB[0][0], acc);

#pragma unroll
    for (int i = 0; i < 4; i++)
#pragma unroll
        for (int j = 0; j < 2; j++) {
            int m = m0 + wm + i * 16 + 4 * lg;           // s base; r adds 0..3
            int n = n0 + wn + j * 16 + lr;
            int b = m >> 11, s = m & 2047;
            int h = n >> 6, dh = n & 63;
            us4 o;
#pragma unroll
            for (int r = 0; r < 4; r++) o[r] = f2bf(acc[i][j][r]);
            *(us4*)&VT[(((size_t)(b * NH + h)) * DH + dh) * SEQ + s] = o;
        }
}

// output projection: A bf16 [4096][1024] @ W0^T -> fp32 [4096][1024]
__global__ __launch_bounds__(256) void gemm_o(const ushort_t* __restrict__ A,
                                              const ushort_t* __restrict__ W,
                                              float* __restrict__ C)
{
    __shared__ ushort_t sA[2][128 * 64];
    __shared__ ushort_t sB[2][64 * 64];
    const int t = threadIdx.x, lane = t & 63, w = t >> 6;
    const int lr = lane & 15, lg = lane >> 4;
    const int wm = (w >> 1) * 64, wn = (w & 1) * 32;
    const int m0 = blockIdx.x * 128, n0 = blockIdx.y * 64;

    f32x4 acc[4][2];
    f32x4 zero = {0.f, 0.f, 0.f, 0.f};
#pragma unroll
    for (int i = 0; i < 4; i++)
#pragma unroll
        for (int j = 0; j < 2; j++) acc[i][j] = zero;
    gemm_core(A, W, m0, n0, t, &sA[0][0], &sB[0][0], acc);

#pragma unroll
    for (int i = 0; i < 4; i++)
#pragma unroll
        for (int j = 0; j < 2; j++)
#pragma unroll
            for (int r = 0; r < 4; r++) {
                int m = m0 + wm + i * 16 + 4 * lg + r;
                int n = n0 + wn + j * 16 + lr;
                C[(size_t)m * D_MODEL + n] = acc[i][j][r];
            }
}

// ---------------------------------------------------------------------------
// Flash attention, swapped-operand 32x32x16 form, KVBLK=128 (2 halves/barrier):
//   S = mfma32(K, Q) for all 128 kv (16 mfma burst), then per 64-col half:
//   {V-reads, online-softmax update, PV} — half-B softmax VALU overlaps
//   half-A PV MFMA (separate pipes). Sequential halves == round-9 update
//   order => numerics identical. Barriers halve (16/loop).
//   P in registers: cvt_pk + shfl_xor(32) + select (verified round 7).
//   sK swizzle ^(row&7)<<4 (128B rows); sVT ^(row&15)<<4 (256B rows, 2-way).
//   setprio(1) around MFMA clusters (T5).
// C/D layout (HW-verified): col=lane&31, row=(r&3)+8*(r>>2)+4*(lane>>5).
// ---------------------------------------------------------------------------
__global__ __launch_bounds__(256, 2) void attn_fwd(const ushort_t* __restrict__ Q,
                                                   const ushort_t* __restrict__ K,
                                                   const ushort_t* __restrict__ VT,
                                                   const float* __restrict__ mask,
                                                   const int* __restrict__ flags,
                                                   ushort_t* __restrict__ O)
{
    __shared__ ushort_t sK[2][128 * 64];    // 128 kv rows x 64 dh
    __shared__ ushort_t sVT[2][64 * 128];   // 64 dh rows x 128 kv

    const int t = threadIdx.x, lane = t & 63, w = t >> 6;
    const int l31 = lane & 31, lh = lane >> 5;
    const int id = blockIdx.x;
    const int bh = (id & 7) * 4 + ((id >> 3) >> 4);   // XCD-contiguous heads
    const int qt = (id >> 3) & 15;
    const int b = bh >> 4, h = bh & 15;
    const int q = qt * 128 + w * 32 + l31;   // lane's q row

    // mask-tile flags for this 128-row q block (2 flag rows ORed); bit = 64-col tile
    unsigned long long blt = __ballot(flags[(qt * 2 + lh) * 32 + l31] != 0);
    const unsigned int fl = (unsigned int)(blt | (blt >> 32));

    // Q fragments: B-operand rows = q, k(d)-slots 16*ks + 8*lh + e
    us8 qfr[4];
#pragma unroll
    for (int ks = 0; ks < 4; ks++)
        qfr[ks] = *(const us8*)(Q + ((size_t)bh * SEQ + q) * DH + ks * 16 + 8 * lh);

    f32x16 acc_o[2];
#pragma unroll
    for (int d = 0; d < 2; d++)
#pragma unroll
        for (int r = 0; r < 16; r++) acc_o[d][r] = 0.f;
    float acc_l = 0.f, m_run = -1e30f;

    const ushort_t* Kb = K + (size_t)bh * SEQ * DH;
    const ushort_t* Vb = VT + (size_t)bh * DH * SEQ;

    // staging: per 128-kv tile, K 16KB (1024 chunks) + V 16KB (1024 chunks)
#define STAGE(kvt_, buf_)                                                     \
    {                                                                         \
        _Pragma("unroll")                                                     \
        for (int r = 0; r < 4; r++) {                                         \
            int j = r * 256 + t;                                              \
            int row = j >> 3, cc = (j & 7) ^ (row & 7);                       \
            gload16(Kb + (size_t)((kvt_) * 128 + row) * DH + cc * 8,          \
                    &sK[buf_][(r * 256 + w * 64) * 8]);                       \
        }                                                                     \
        _Pragma("unroll")                                                     \
        for (int r = 0; r < 4; r++) {                                         \
            int j = r * 256 + t;                                              \
            int row = j >> 4, cc = (j & 15) ^ (row & 15);                     \
            gload16(Vb + (size_t)row * SEQ + (kvt_) * 128 + cc * 8,           \
                    &sVT[buf_][(r * 256 + w * 64) * 8]);                      \
        }                                                                     \
    }

    STAGE(0, 0);
    __syncthreads();

    for (int kvt = 0; kvt < SEQ / 128; ++kvt) {
        const int cur = kvt & 1;
        const char* cK = (const char*)sK[cur];
        const char* cV = (const char*)sVT[cur];

        // ---- S = K Q^T for all 128 kv: sacc[kb][r], kcol = kb*32+crow(r,lh) ----
        f32x16 sacc[4];
#pragma unroll
        for (int kb = 0; kb < 4; kb++)
#pragma unroll
            for (int r = 0; r < 16; r++) sacc[kb][r] = 0.f;
        __builtin_amdgcn_s_setprio(1);
#pragma unroll
        for (int ks = 0; ks < 4; ks++)
#pragma unroll
            for (int kb = 0; kb < 4; kb++) {
                int row = kb * 32 + l31;
                int by = (row * 128 + (ks * 16 + 8 * lh) * 2) ^ ((row & 7) << 4);
                us8 kf = *(const us8*)(cK + by);
                sacc[kb] = mfma32(kf, qfr[ks], sacc[kb]);
            }
        __builtin_amdgcn_s_setprio(0);

        // ---- stage next tile; loads hide under softmax + PV of both halves ----
        if (kvt + 1 < SEQ / 128) STAGE(kvt + 1, cur ^ 1);

        // ---- two sequential 64-col halves (== round-9 per-tile updates) ----
#pragma unroll
        for (int hf = 0; hf < 2; hf++) {
            // V-frag reads for this half (issued early; 2-way banked)
            us8 vf[4][2];
#pragma unroll
            for (int ks = 0; ks < 4; ks++)
#pragma unroll
                for (int dblk = 0; dblk < 2; dblk++) {
                    int row = dblk * 32 + l31;
                    int by = (row * 256 + hf * 128 + ks * 32 + 16 * lh)
                             ^ ((row & 15) << 4);
                    vf[ks][dblk] = *(const us8*)(cV + by);
                }

            // additive mask (log2; skipped when 64-col tile all-zero)
            if ((fl >> (2 * kvt + hf)) & 1u) {
#pragma unroll
                for (int kk = 0; kk < 2; kk++) {
                    const int kb = 2 * hf + kk;
#pragma unroll
                    for (int r = 0; r < 16; r++) {
                        int kcol = kb * 32 + (r & 3) + 8 * (r >> 2) + 4 * lh;
                        sacc[kb][r] += mask[(size_t)q * SEQ + kvt * 128 + kcol] * LOG2E;
                    }
                }
            }

            // row max over this half: in-lane tree + 1 cross-half shfl
            float mx = sacc[2 * hf][0];
#pragma unroll
            for (int kk = 0; kk < 2; kk++)
#pragma unroll
                for (int r = 0; r < 16; r++) mx = fmaxf(mx, sacc[2 * hf + kk][r]);
            mx = fmaxf(mx, __shfl_xor(mx, 32));

            // defer-max rescale (THR = 8*log2e)
            bool need = mx > m_run + 11.541560f;
            if (__any((int)need)) {
                float mn = fmaxf(m_run, mx);
                float sc = exp2_fast(m_run - mn);
                m_run = mn;
                acc_l *= sc;
#pragma unroll
                for (int d = 0; d < 2; d++)
#pragma unroll
                    for (int r = 0; r < 16; r++) acc_o[d][r] *= sc;
            }

            // P = exp2(S - m) in place; l partial sum
            float rs = 0.f;
#pragma unroll
            for (int kk = 0; kk < 2; kk++)
#pragma unroll
                for (int r = 0; r < 16; r++) {
                    float p = exp2_fast(sacc[2 * hf + kk][r] - m_run);
                    sacc[2 * hf + kk][r] = p;
                    rs += p;
                }
            rs += __shfl_xor(rs, 32);
            acc_l += rs;

            // PV: P B-frags via cvt_pk + cross-half shfl + select (verified)
            __builtin_amdgcn_s_setprio(1);
#pragma unroll
            for (int ks = 0; ks < 4; ks++) {
                const int kb = 2 * hf + (ks >> 1), u = ks & 1;
                unsigned int W0 = cvtpk(sacc[kb][8 * u + 0], sacc[kb][8 * u + 1]);
                unsigned int W1 = cvtpk(sacc[kb][8 * u + 2], sacc[kb][8 * u + 3]);
                unsigned int W2 = cvtpk(sacc[kb][8 * u + 4], sacc[kb][8 * u + 5]);
                unsigned int W3 = cvtpk(sacc[kb][8 * u + 6], sacc[kb][8 * u + 7]);
                unsigned int X0 = (unsigned int)__shfl_xor((int)W0, 32);
                unsigned int X1 = (unsigned int)__shfl_xor((int)W1, 32);
                unsigned int X2 = (unsigned int)__shfl_xor((int)W2, 32);
                unsigned int X3 = (unsigned int)__shfl_xor((int)W3, 32);
                u32x4 pw;
                pw[0] = lh ? X2 : W0;
                pw[1] = lh ? X3 : W1;
                pw[2] = lh ? W2 : X0;
                pw[3] = lh ? W3 : X1;
                us8 pf = __builtin_bit_cast(us8, pw);
#pragma unroll
                for (int dblk = 0; dblk < 2; dblk++)
                    acc_o[dblk] = mfma32(vf[ks][dblk], pf, acc_o[dblk]);
            }
            __builtin_amdgcn_s_setprio(0);
        }

        __syncthreads();   // drains stage(kvt+1); protects buf reuse
    }

    // ---- normalize + write [B*S][D] bf16 (d = dblk*32 + 8g + 4lh + 0..3) ----
    float inv = 1.f / acc_l;
    ushort_t* Orow = O + ((size_t)(b * SEQ) + q) * D_MODEL + h * DH;
#pragma unroll
    for (int dblk = 0; dblk < 2; dblk++)
#pragma unroll
        for (int g = 0; g < 4; g++) {
            unsigned int lo = cvtpk(acc_o[dblk][4 * g + 0] * inv,
                                    acc_o[dblk][4 * g + 1] * inv);
            unsigned int hi = cvtpk(acc_o[dblk][4 * g + 2] * inv,
                                    acc_o[dblk][4 * g + 3] * inv);
            uint2 pr; pr.x = lo; pr.y = hi;
            *(uint2*)(Orow + dblk * 32 + 8 * g + 4 * lh) = pr;
        }
#undef STAGE
}

// ---------------------------------------------------------------------------
extern "C" void kernel_launch(void* const* d_in, const int* in_sizes, int n_in,
                              void* d_out, int out_size, void* d_ws, size_t ws_size,
                              hipStream_t stream)
{
    const float* qx   = (const float*)d_in[0];
    const float* kx   = (const float*)d_in[1];
    const float* vx   = (const float*)d_in[2];
    const float* mask = (const float*)d_in[3];
    const float* wq   = (const float*)d_in[4];
    const float* wk   = (const float*)d_in[5];
    const float* wv   = (const float*)d_in[6];
    const float* w0   = (const float*)d_in[7];
    float* out = (float*)d_out;

    char* ws = (char*)d_ws;
    const size_t MB = 1024 * 1024;
    ushort_t* A0 = (ushort_t*)(ws);                 // 8 MB (qx bf16, then vx bf16)
    ushort_t* A1 = (ushort_t*)(ws + 8 * MB);        // 8 MB (kx bf16, then AO)
    ushort_t* Wq = (ushort_t*)(ws + 16 * MB);       // 2 MB each
    ushort_t* Wk = (ushort_t*)(ws + 18 * MB);
    ushort_t* Wv = (ushort_t*)(ws + 20 * MB);
    ushort_t* W0 = (ushort_t*)(ws + 22 * MB);
    ushort_t* VT = (ushort_t*)(ws + 24 * MB);       // [B,H,Dh,S] bf16, 8 MB
    int* flags   = (int*)(ws + 32 * MB);            // [32][32]
    ushort_t* AO = A1;                              // attn out reuses A1
    // Q and K (bf16, [B,H,S,Dh]) live in d_out until attn consumes them
    ushort_t* Qb = (ushort_t*)d_out;
    ushort_t* Kb = (ushort_t*)d_out + 4 * MB;       // +8 MB bytes

    hipMemsetAsync(flags, 0, 32 * 32 * sizeof(int), stream);
    mask_flags<<<dim3(32, 32), 256, 0, stream>>>(mask, flags);

    // weights fp32 -> bf16 (one fused launch)
    conv_multi<<<dim3(256, 1, 4), 256, 0, stream>>>(wq, Wq, wk, Wk, wv, Wv, w0, W0, 262144);
    // qx, kx fp32 -> bf16
    conv_multi<<<dim3(1024, 1, 2), 256, 0, stream>>>(qx, A0, kx, A1, qx, A0, qx, A0, 1048576);

    gemm_qk<<<dim3(32, 16, 2), 256, 0, stream>>>(A0, A1, Wq, Wk, Qb, Kb);

    // vx fp32 -> bf16 (A0 free after gemm_qk)
    conv_multi<<<dim3(1024, 1, 1), 256, 0, stream>>>(vx, A0, vx, A0, vx, A0, vx, A0, 1048576);
    gemm_v<<<dim3(32, 16), 256, 0, stream>>>(A0, Wv, VT);

    attn_fwd<<<512, 256, 0, stream>>>(Qb, Kb, VT, mask, flags, AO);

    gemm_o<<<dim3(32, 16), 256, 0, stream>>>(AO, W0, out);
}